// Round 11
// baseline (580.849 us; speedup 1.0000x reference)
//
#include <hip/hip_runtime.h>
#include <float.h>
#include <math.h>
#include <stdint.h>

#define T_ 1024
#define D_ 1024
#define H_ 16
#define HD_ 64
#define E_ 8
#define F_ 2560
#define D3_ 3072
#define F2_ 5120

// ---- workspace layout (float offsets) ----
#define WS_H    0u         // LN1 out (bf16); later reused as SACC (fp32 split-K accum)
#define WS_QKV  1048576u   // 3M   qkv (T,3D) fp32
#define WS_ATTN 4194304u   // attention out (T,D) bf16
#define WS_X2   5242880u   // x + attn proj (T,D) fp32
#define WS_H2   6291456u   // LN2 out (T,D) bf16
#define WS_A    7340032u   // gated activation (T,F) bf16
#define WS_GW   9961472u
#define WS_GI   9962496u
#define WS_OFFS 9963520u
#define WS_PERM 9963536u
#define WS_H12  10485760u  // 2 x (T,F2) fp32 split-K partial sums (84 MB total)

typedef short short8 __attribute__((ext_vector_type(8)));
typedef short short4v __attribute__((ext_vector_type(4)));
typedef __bf16 bf16x8 __attribute__((ext_vector_type(8)));
typedef float floatx4 __attribute__((ext_vector_type(4)));

union FragU { short8 s; bf16x8 b; };

__device__ __forceinline__ short f2bf(float f) {
    union { float f; uint32_t u; } a; a.f = f;
    uint32_t r = a.u + 0x7fffu + ((a.u >> 16) & 1u);
    return (short)(r >> 16);
}

__device__ __forceinline__ void cvt16(const float4& a0, const float4& a1,
                                      const float4& a2, const float4& a3,
                                      short8& c0, short8& c1) {
    c0[0]=f2bf(a0.x); c0[1]=f2bf(a0.y); c0[2]=f2bf(a0.z); c0[3]=f2bf(a0.w);
    c0[4]=f2bf(a1.x); c0[5]=f2bf(a1.y); c0[6]=f2bf(a1.z); c0[7]=f2bf(a1.w);
    c1[0]=f2bf(a2.x); c1[1]=f2bf(a2.y); c1[2]=f2bf(a2.z); c1[3]=f2bf(a2.w);
    c1[4]=f2bf(a3.x); c1[5]=f2bf(a3.y); c1[6]=f2bf(a3.z); c1[7]=f2bf(a3.w);
}

// ===================== MFMA GEMM cores =====================
// Tile: BM=128, BN=64, BK=32. 256 thr = 4 waves (2x2), wave tile 64x32.
// A operand is bf16 in global (pre-rounded by producers).
// K-loop unrolled x2 with two static register sets.
#define GEMM_IDS \
    const int tid  = threadIdx.x;                 \
    const int a_m  = tid >> 1;                    \
    const int a_kh = (tid & 1) * 16;              \
    const int lane = tid & 63, wave = tid >> 6;   \
    const int wm = wave & 1,  wn = wave >> 1;     \
    const int quad = lane >> 4, lm = lane & 15;

// split-K accumulating GEMM (optionally token-routed): Cacc += A@B
// blockIdx.y: sk = y % nsk, e = y / nsk.  blockIdx.z = row block (mostly-dead dim last)
__global__ __launch_bounds__(256) void gemm_mfma_acc(
    const short* __restrict__ A, int lda,      // bf16 activations
    const float* __restrict__ B, int ldb, long sB,
    const int* __restrict__ offs, const int* __restrict__ perm,
    float* __restrict__ Cacc, int ldc, int K, int nsk)
{
    const int sk = blockIdx.y % nsk;
    const int e  = blockIdx.y / nsk;
    int off = 0, Ne = T_;
    if (offs) { off = offs[e]; Ne = offs[e+1] - off; }
    const int row0 = blockIdx.z * 128;
    if (row0 >= Ne) return;
    const int col0 = blockIdx.x * 64;
    B += (long)e * sB;

    __shared__ __align__(16) short As[4*128*8];
    __shared__ __align__(16) short Bs[64*40];
    __shared__ int toks[128];
    GEMM_IDS
    const int b_n = tid >> 2, b_kc = tid & 3;
    if (tid < 128) {
        int r = row0 + tid;
        toks[tid] = offs ? ((r < Ne) ? perm[off + r] : -1) : r;
    }
    __syncthreads();

    floatx4 acc[4][2];
    #pragma unroll
    for (int i=0;i<4;i++)
        #pragma unroll
        for (int j=0;j<2;j++) acc[i][j] = (floatx4){0.f,0.f,0.f,0.f};

    const int tokA = toks[a_m];
    const short* apx = (tokA >= 0) ? (A + (size_t)tokA * lda + a_kh) : nullptr;
    const float* bpx = B + (size_t)(b_kc*8) * ldb + col0 + b_n;
    const int kcA = (tid & 1) * 2;
    const int Kp = K / nsk;
    const int koff = sk * Kp, kend = koff + Kp;

    short8 sA0 = {0,0,0,0,0,0,0,0}, sA1 = sA0, sB0 = sA0, sB1 = sA0;
    float bvA[8], bvB[8];
    if (apx) {
        sA0 = *(const short8*)(apx + koff);
        sA1 = *(const short8*)(apx + koff + 8);
        sB0 = *(const short8*)(apx + koff + 32);
        sB1 = *(const short8*)(apx + koff + 40);
    }
    {
        const float* bp2 = bpx + (size_t)koff * ldb;
        #pragma unroll
        for (int j=0;j<8;j++) bvA[j] = bp2[(size_t)j*ldb];
        bp2 += (size_t)32 * ldb;
        #pragma unroll
        for (int j=0;j<8;j++) bvB[j] = bp2[(size_t)j*ldb];
    }

#define GA_STEP(S0,S1,BV,kpre)                                            \
    __syncthreads();                                                      \
    {                                                                     \
        short8 cb;                                                        \
        _Pragma("unroll")                                                 \
        for (int j=0;j<8;j++) cb[j] = f2bf(BV[j]);                        \
        *(short8*)&As[((kcA  )*128 + a_m)*8] = S0;                        \
        *(short8*)&As[((kcA+1)*128 + a_m)*8] = S1;                        \
        *(short8*)&Bs[b_n*40 + b_kc*8] = cb;                              \
    }                                                                     \
    __syncthreads();                                                      \
    if ((kpre) < kend) {                                                  \
        if (apx) {                                                        \
            S0 = *(const short8*)(apx + (kpre));                          \
            S1 = *(const short8*)(apx + (kpre) + 8);                      \
        }                                                                 \
        const float* bp2 = bpx + (size_t)(kpre) * ldb;                    \
        _Pragma("unroll")                                                 \
        for (int j=0;j<8;j++) BV[j] = bp2[(size_t)j*ldb];                 \
    }                                                                     \
    {                                                                     \
        FragU fa[4], fb[2];                                               \
        _Pragma("unroll")                                                 \
        for (int i=0;i<4;i++) fa[i].s = *(short8*)&As[(quad*128 + wm*64 + i*16 + lm)*8]; \
        _Pragma("unroll")                                                 \
        for (int j=0;j<2;j++) fb[j].s = *(short8*)&Bs[(wn*32 + j*16 + lm)*40 + quad*8];  \
        _Pragma("unroll")                                                 \
        for (int i=0;i<4;i++)                                             \
            _Pragma("unroll")                                             \
            for (int j=0;j<2;j++)                                         \
                acc[i][j] = __builtin_amdgcn_mfma_f32_16x16x32_bf16(fa[i].b, fb[j].b, acc[i][j], 0,0,0); \
    }

    for (int k0 = koff; k0 < kend; k0 += 64) {
        GA_STEP(sA0, sA1, bvA, k0 + 64)
        GA_STEP(sB0, sB1, bvB, k0 + 96)
    }
#undef GA_STEP

    #pragma unroll
    for (int i=0;i<4;i++)
        #pragma unroll
        for (int j=0;j<2;j++) {
            int col = col0 + wn*32 + j*16 + lm;
            #pragma unroll
            for (int r=0;r<4;r++) {
                int tk = toks[wm*64 + i*16 + quad*4 + r];
                if (tk >= 0) atomicAdd(&Cacc[(size_t)tk*ldc + col], acc[i][j][r]);
            }
        }
}

// MoE fc as split-K=2 GEMM, BN=64, direct (non-atomic) stores into two
// per-split fp32 buffers Cout[sk][tok][F2]. GLU applied by glu_kernel after.
__global__ __launch_bounds__(256) void gemm_fc_sk(
    const short* __restrict__ A, const float* __restrict__ B,
    const int* __restrict__ offs, const int* __restrict__ perm,
    float* __restrict__ Cout)
{
    const int sk = blockIdx.y & 1;
    const int e  = blockIdx.y >> 1;
    const int off = offs[e], Ne = offs[e+1] - off;
    const int row0 = blockIdx.z * 128;
    if (row0 >= Ne) return;
    const int col0 = blockIdx.x * 64;
    const float* Bw = B + (size_t)e * D_ * F2_;

    __shared__ __align__(16) short As[4*128*8];
    __shared__ __align__(16) short Bs[64*40];
    __shared__ int toks[128];
    GEMM_IDS
    const int b_n = tid >> 2, b_kc = tid & 3;
    if (tid < 128) {
        int r = row0 + tid;
        toks[tid] = (r < Ne) ? perm[off + r] : -1;
    }
    __syncthreads();

    floatx4 acc[4][2];
    #pragma unroll
    for (int i=0;i<4;i++)
        #pragma unroll
        for (int j=0;j<2;j++) acc[i][j] = (floatx4){0.f,0.f,0.f,0.f};

    const int tokA = toks[a_m];
    const short* apx = (tokA >= 0) ? (A + (size_t)tokA * D_ + a_kh) : nullptr;
    const float* bpx = Bw + (size_t)(b_kc*8) * F2_ + col0 + b_n;
    const int kcA = (tid & 1) * 2;
    const int koff = sk * (D_/2), kend = koff + (D_/2);

    short8 sA0 = {0,0,0,0,0,0,0,0}, sA1 = sA0, sB0 = sA0, sB1 = sA0;
    float bvA[8], bvB[8];
    if (apx) {
        sA0 = *(const short8*)(apx + koff);
        sA1 = *(const short8*)(apx + koff + 8);
        sB0 = *(const short8*)(apx + koff + 32);
        sB1 = *(const short8*)(apx + koff + 40);
    }
    {
        const float* bp2 = bpx + (size_t)koff * F2_;
        #pragma unroll
        for (int j=0;j<8;j++) bvA[j] = bp2[(size_t)j*F2_];
        bp2 += (size_t)32 * F2_;
        #pragma unroll
        for (int j=0;j<8;j++) bvB[j] = bp2[(size_t)j*F2_];
    }

#define FC_STEP(S0,S1,BV,kpre)                                            \
    __syncthreads();                                                      \
    {                                                                     \
        short8 cb;                                                        \
        _Pragma("unroll")                                                 \
        for (int j=0;j<8;j++) cb[j] = f2bf(BV[j]);                        \
        *(short8*)&As[((kcA  )*128 + a_m)*8] = S0;                        \
        *(short8*)&As[((kcA+1)*128 + a_m)*8] = S1;                        \
        *(short8*)&Bs[b_n*40 + b_kc*8] = cb;                              \
    }                                                                     \
    __syncthreads();                                                      \
    if ((kpre) < kend) {                                                  \
        if (apx) {                                                        \
            S0 = *(const short8*)(apx + (kpre));                          \
            S1 = *(const short8*)(apx + (kpre) + 8);                      \
        }                                                                 \
        const float* bp2 = bpx + (size_t)(kpre) * F2_;                    \
        _Pragma("unroll")                                                 \
        for (int j=0;j<8;j++) BV[j] = bp2[(size_t)j*F2_];                 \
    }                                                                     \
    {                                                                     \
        FragU fa[4], fb[2];                                               \
        _Pragma("unroll")                                                 \
        for (int i=0;i<4;i++) fa[i].s = *(short8*)&As[(quad*128 + wm*64 + i*16 + lm)*8]; \
        _Pragma("unroll")                                                 \
        for (int j=0;j<2;j++) fb[j].s = *(short8*)&Bs[(wn*32 + j*16 + lm)*40 + quad*8];  \
        _Pragma("unroll")                                                 \
        for (int i=0;i<4;i++)                                             \
            _Pragma("unroll")                                             \
            for (int j=0;j<2;j++)                                         \
                acc[i][j] = __builtin_amdgcn_mfma_f32_16x16x32_bf16(fa[i].b, fb[j].b, acc[i][j], 0,0,0); \
    }

    for (int k0 = koff; k0 < kend; k0 += 64) {
        FC_STEP(sA0, sA1, bvA, k0 + 64)
        FC_STEP(sB0, sB1, bvB, k0 + 96)
    }
#undef FC_STEP

    #pragma unroll
    for (int i=0;i<4;i++)
        #pragma unroll
        for (int j=0;j<2;j++) {
            int col = col0 + wn*32 + j*16 + lm;
            #pragma unroll
            for (int r=0;r<4;r++) {
                int tk = toks[wm*64 + i*16 + quad*4 + r];
                if (tk >= 0)
                    Cout[((size_t)(sk*T_ + tk))*F2_ + col] = acc[i][j][r];
            }
        }
}

// GLU epilogue: sum the two split-K halves, add bias, x1 * gelu(x2), bf16 out.
__global__ __launch_bounds__(256) void glu_kernel(
    const float* __restrict__ h12, const float* __restrict__ fcb,
    const int* __restrict__ gi, short* __restrict__ aout)
{
    const int t = blockIdx.x, tid = threadIdx.x;
    const int e = gi[t];
    const float* p0 = h12 + (size_t)t * F2_;
    const float* p1 = h12 + (size_t)(T_ + t) * F2_;
    const float* fb = fcb + (size_t)e * F2_;
    for (int c = tid*4; c < F_; c += 1024) {
        float4 x0 = *(const float4*)(p0 + c);
        float4 x1 = *(const float4*)(p1 + c);
        float4 xb = *(const float4*)(fb + c);
        float4 g0 = *(const float4*)(p0 + F_ + c);
        float4 g1 = *(const float4*)(p1 + F_ + c);
        float4 gb = *(const float4*)(fb + F_ + c);
        float a1[4] = {x0.x+x1.x+xb.x, x0.y+x1.y+xb.y, x0.z+x1.z+xb.z, x0.w+x1.w+xb.w};
        float a2[4] = {g0.x+g1.x+gb.x, g0.y+g1.y+gb.y, g0.z+g1.z+gb.z, g0.w+g1.w+gb.w};
        short4v o;
        #pragma unroll
        for (int j=0;j<4;j++) {
            float g = a2[j] * 0.5f * (1.0f + erff(a2[j] * 0.70710678118654752f));
            o[j] = f2bf(a1[j] * g);
        }
        *(short4v*)(aout + (size_t)t*F_ + c) = o;
    }
}

// fill buf rows with a bias vector (pre-fill for split-K accumulation)
__global__ __launch_bounds__(256) void bias_fill(
    const float* __restrict__ bias, float* __restrict__ buf, int width)
{
    const int row = blockIdx.x, tid = threadIdx.x;
    for (int c = tid*4; c < width; c += 1024) {
        float4 b = *(const float4*)(bias + c);
        *(float4*)(buf + (size_t)row*width + c) = b;
    }
}

// ===================== MFMA flash attention =====================
__global__ __launch_bounds__(128) void flash_attn(
    const float* __restrict__ qkv, const int* __restrict__ ids,
    short* __restrict__ attnout)
{
    const int h  = blockIdx.y;
    const int q0 = blockIdx.x * 32;
    const int tid = threadIdx.x;
    const int lane = tid & 63, w = tid >> 6;
    const int quad = lane >> 4, lm = lane & 15;

    __shared__ __align__(16) short Qs[32*72];
    __shared__ __align__(16) short Ks[64*72];
    __shared__ __align__(16) short Vt[64*72];
    __shared__ __align__(16) short Ps[2][16*72];
    __shared__ int globf[32];

    {
        int row = tid >> 2, c = (tid & 3) * 16;
        const float* qp = qkv + (size_t)(q0 + row) * D3_ + h * HD_ + c;
        float4 f0 = *(const float4*)(qp);
        float4 f1 = *(const float4*)(qp + 4);
        float4 f2 = *(const float4*)(qp + 8);
        float4 f3 = *(const float4*)(qp + 12);
        short8 s0, s1;
        cvt16(f0, f1, f2, f3, s0, s1);
        *(short8*)&Qs[row*72 + c]     = s0;
        *(short8*)&Qs[row*72 + c + 8] = s1;
    }
    if (tid < 32) {
        int id = ids[q0 + tid];
        globf[tid] = (id >= 2 && id <= 7) ? 1 : 0;
    }
    __syncthreads();

    FragU QA[2];
    #pragma unroll
    for (int s = 0; s < 2; s++)
        QA[s].s = *(short8*)&Qs[(w*16 + lm)*72 + s*32 + quad*8];

    int any = 0;
    #pragma unroll
    for (int i = 0; i < 32; i++) any |= globf[i];
    const int nt = any ? (T_/64) : ((q0 + 31) >> 6) + 1;

    int gq[4]; int qidx[4];
    #pragma unroll
    for (int r = 0; r < 4; r++) {
        int ql = w*16 + quad*4 + r;
        qidx[r] = q0 + ql;
        gq[r] = globf[ql];
    }

    float mrow[4] = {-1e30f, -1e30f, -1e30f, -1e30f};
    float lrow[4] = {0.f, 0.f, 0.f, 0.f};
    floatx4 Oacc[4];
    #pragma unroll
    for (int n = 0; n < 4; n++) Oacc[n] = (floatx4){0.f, 0.f, 0.f, 0.f};

    for (int kt = 0; kt < nt; kt++) {
        __syncthreads();
        #pragma unroll
        for (int rep = 0; rep < 2; rep++) {
            int key = (tid >> 2) + rep*32;
            int c = (tid & 3) * 16;
            const float* kp = qkv + (size_t)(kt*64 + key) * D3_ + D_ + h*HD_ + c;
            float4 f0 = *(const float4*)(kp);
            float4 f1 = *(const float4*)(kp + 4);
            float4 f2 = *(const float4*)(kp + 8);
            float4 f3 = *(const float4*)(kp + 12);
            short8 s0, s1;
            cvt16(f0, f1, f2, f3, s0, s1);
            *(short8*)&Ks[key*72 + c]     = s0;
            *(short8*)&Ks[key*72 + c + 8] = s1;
        }
        #pragma unroll
        for (int rep = 0; rep < 8; rep++) {
            int lin = tid + rep*128;
            int key = lin >> 4;
            int c = (lin & 15) * 4;
            const float* vp = qkv + (size_t)(kt*64 + key) * D3_ + 2*D_ + h*HD_ + c;
            float4 f = *(const float4*)vp;
            Vt[(c+0)*72 + key] = f2bf(f.x);
            Vt[(c+1)*72 + key] = f2bf(f.y);
            Vt[(c+2)*72 + key] = f2bf(f.z);
            Vt[(c+3)*72 + key] = f2bf(f.w);
        }
        __syncthreads();

        floatx4 Sv[4];
        #pragma unroll
        for (int n = 0; n < 4; n++) {
            Sv[n] = (floatx4){0.f, 0.f, 0.f, 0.f};
            #pragma unroll
            for (int s = 0; s < 2; s++) {
                FragU KB;
                KB.s = *(short8*)&Ks[(n*16 + lm)*72 + s*32 + quad*8];
                Sv[n] = __builtin_amdgcn_mfma_f32_16x16x32_bf16(QA[s].b, KB.b, Sv[n], 0, 0, 0);
            }
        }
        #pragma unroll
        for (int n = 0; n < 4; n++) {
            int key = kt*64 + n*16 + lm;
            #pragma unroll
            for (int r = 0; r < 4; r++) {
                float v = Sv[n][r] * 0.125f;
                if (!gq[r] && key > qidx[r]) v = -1e30f;
                Sv[n][r] = v;
            }
        }
        float mnew[4], alpha[4], tsum[4];
        #pragma unroll
        for (int r = 0; r < 4; r++) {
            float tm = fmaxf(fmaxf(Sv[0][r], Sv[1][r]), fmaxf(Sv[2][r], Sv[3][r]));
            #pragma unroll
            for (int x = 1; x < 16; x <<= 1) tm = fmaxf(tm, __shfl_xor(tm, x));
            mnew[r] = fmaxf(mrow[r], tm);
            alpha[r] = __expf(mrow[r] - mnew[r]);
            mrow[r] = mnew[r];
            tsum[r] = 0.f;
        }
        #pragma unroll
        for (int n = 0; n < 4; n++) {
            #pragma unroll
            for (int r = 0; r < 4; r++) {
                float p = __expf(Sv[n][r] - mnew[r]);
                tsum[r] += p;
                Ps[w][(quad*4 + r)*72 + n*16 + lm] = f2bf(p);
            }
        }
        #pragma unroll
        for (int r = 0; r < 4; r++) {
            #pragma unroll
            for (int x = 1; x < 16; x <<= 1) tsum[r] += __shfl_xor(tsum[r], x);
            lrow[r] = lrow[r] * alpha[r] + tsum[r];
        }
        #pragma unroll
        for (int n = 0; n < 4; n++)
            #pragma unroll
            for (int r = 0; r < 4; r++) Oacc[n][r] *= alpha[r];

        #pragma unroll
        for (int s = 0; s < 2; s++) {
            FragU PA;
            PA.s = *(short8*)&Ps[w][lm*72 + s*32 + quad*8];
            #pragma unroll
            for (int n = 0; n < 4; n++) {
                FragU VB;
                VB.s = *(short8*)&Vt[(n*16 + lm)*72 + s*32 + quad*8];
                Oacc[n] = __builtin_amdgcn_mfma_f32_16x16x32_bf16(PA.b, VB.b, Oacc[n], 0, 0, 0);
            }
        }
    }

    #pragma unroll
    for (int n = 0; n < 4; n++)
        #pragma unroll
        for (int r = 0; r < 4; r++) {
            float o = Oacc[n][r] / lrow[r];
            attnout[(size_t)qidx[r]*D_ + h*HD_ + n*16 + lm] = f2bf(o);
        }
}

// ===================== epilogues =====================
__global__ __launch_bounds__(256) void ep_attn(
    const float* __restrict__ x, const float* __restrict__ sacc,
    const float* __restrict__ aob, float* __restrict__ x2)
{
    int row = blockIdx.x, tid = threadIdx.x;
    float4 xv = ((const float4*)(x + (size_t)row*D_))[tid];
    float4 sv = ((const float4*)(sacc + (size_t)row*D_))[tid];
    float4 bv = ((const float4*)aob)[tid];
    float4 o;
    o.x = xv.x + sv.x + bv.x; o.y = xv.y + sv.y + bv.y;
    o.z = xv.z + sv.z + bv.z; o.w = xv.w + sv.w + bv.w;
    ((float4*)(x2 + (size_t)row*D_))[tid] = o;
}

__global__ __launch_bounds__(256) void ep_moe(
    const float* __restrict__ x2, const float* __restrict__ sacc,
    const float* __restrict__ eob, const float* __restrict__ gw,
    const int* __restrict__ gi, float* __restrict__ out)
{
    int row = blockIdx.x, tid = threadIdx.x;
    float g = gw[row];
    int e = gi[row];
    float4 xv = ((const float4*)(x2 + (size_t)row*D_))[tid];
    float4 sv = ((const float4*)(sacc + (size_t)row*D_))[tid];
    float4 bv = ((const float4*)(eob + (size_t)e*D_))[tid];
    float4 o;
    o.x = xv.x + g*(sv.x + bv.x); o.y = xv.y + g*(sv.y + bv.y);
    o.z = xv.z + g*(sv.z + bv.z); o.w = xv.w + g*(sv.w + bv.w);
    ((float4*)(out + (size_t)row*D_))[tid] = o;
}

// ===================== small kernels =====================
__global__ __launch_bounds__(256) void ln_kernel(
    const float* __restrict__ x, const float* __restrict__ w,
    const float* __restrict__ b, short* __restrict__ out)   // bf16 out
{
    const int row = blockIdx.x, tid = threadIdx.x;
    const int lane = tid & 63, wave = tid >> 6;
    float4 v = ((const float4*)(x + (size_t)row * D_))[tid];
    float s  = v.x + v.y + v.z + v.w;
    float sq = v.x*v.x + v.y*v.y + v.z*v.z + v.w*v.w;
    #pragma unroll
    for (int off = 32; off; off >>= 1) {
        s  += __shfl_down(s, off);
        sq += __shfl_down(sq, off);
    }
    __shared__ float rs[4], rq[4], mv[2];
    if (lane == 0) { rs[wave] = s; rq[wave] = sq; }
    __syncthreads();
    if (tid == 0) {
        float ts = rs[0]+rs[1]+rs[2]+rs[3];
        float tq = rq[0]+rq[1]+rq[2]+rq[3];
        float mean = ts * (1.0f / D_);
        float var  = tq * (1.0f / D_) - mean*mean;
        mv[0] = mean; mv[1] = rsqrtf(var + 1e-5f);
    }
    __syncthreads();
    float mean = mv[0], rstd = mv[1];
    float4 wv = ((const float4*)w)[tid];
    float4 bv = ((const float4*)b)[tid];
    short4v o;
    o[0] = f2bf((v.x-mean)*rstd*wv.x + bv.x);
    o[1] = f2bf((v.y-mean)*rstd*wv.y + bv.y);
    o[2] = f2bf((v.z-mean)*rstd*wv.z + bv.z);
    o[3] = f2bf((v.w-mean)*rstd*wv.w + bv.w);
    ((short4v*)(out + (size_t)row * D_))[tid] = o;
}

__global__ __launch_bounds__(256) void rope_kernel(float* __restrict__ qkv)
{
    int gid = blockIdx.x * 256 + threadIdx.x;
    int t = gid >> 9;
    int r = gid & 511;
    int h = r >> 5;
    int d = r & 31;
    float inv = exp2f((float)d * -0.4152410118609203f);
    float fr = (float)t * inv;
    float s, c;
    sincosf(fr, &s, &c);
    float* base = qkv + (size_t)t*D3_ + h*HD_ + d;
    float q1 = base[0], q2 = base[32];
    base[0]  = q1*c - q2*s;
    base[32] = q1*s + q2*c;
    float* kb = base + D_;
    float k1 = kb[0], k2 = kb[32];
    kb[0]  = k1*c - k2*s;
    kb[32] = k1*s + k2*c;
}

__global__ __launch_bounds__(256) void ln2_gate_kernel(
    const float* __restrict__ x2, const float* __restrict__ w,
    const float* __restrict__ b, const float* __restrict__ gwm,
    const float* __restrict__ gbv, short* __restrict__ h2,   // bf16 out
    int* __restrict__ gi, float* __restrict__ gw)
{
    const int row = blockIdx.x, tid = threadIdx.x;
    const int lane = tid & 63, wave = tid >> 6;
    float4 v = ((const float4*)(x2 + (size_t)row * D_))[tid];
    float s  = v.x + v.y + v.z + v.w;
    float sq = v.x*v.x + v.y*v.y + v.z*v.z + v.w*v.w;
    #pragma unroll
    for (int off = 32; off; off >>= 1) {
        s  += __shfl_down(s, off);
        sq += __shfl_down(sq, off);
    }
    __shared__ float rs[4], rq[4], mv[2];
    if (lane == 0) { rs[wave] = s; rq[wave] = sq; }
    __syncthreads();
    if (tid == 0) {
        float ts = rs[0]+rs[1]+rs[2]+rs[3];
        float tq = rq[0]+rq[1]+rq[2]+rq[3];
        float mean = ts * (1.0f / D_);
        float var  = tq * (1.0f / D_) - mean*mean;
        mv[0] = mean; mv[1] = rsqrtf(var + 1e-5f);
    }
    __syncthreads();
    float mean = mv[0], rstd = mv[1];
    float4 wv = ((const float4*)w)[tid];
    float4 bv = ((const float4*)b)[tid];
    float hv[4];
    hv[0] = (v.x-mean)*rstd*wv.x + bv.x;
    hv[1] = (v.y-mean)*rstd*wv.y + bv.y;
    hv[2] = (v.z-mean)*rstd*wv.z + bv.z;
    hv[3] = (v.w-mean)*rstd*wv.w + bv.w;
    short4v o;
    o[0]=f2bf(hv[0]); o[1]=f2bf(hv[1]); o[2]=f2bf(hv[2]); o[3]=f2bf(hv[3]);
    ((short4v*)(h2 + (size_t)row * D_))[tid] = o;

    float acc[E_] = {};
    int c = tid * 4;
    #pragma unroll
    for (int j = 0; j < 4; j++) {
        const float* gr = gwm + (size_t)(c+j) * E_;
        #pragma unroll
        for (int e = 0; e < E_; e++) acc[e] += hv[j] * gr[e];
    }
    #pragma unroll
    for (int off = 32; off; off >>= 1)
        #pragma unroll
        for (int e = 0; e < E_; e++) acc[e] += __shfl_down(acc[e], off);
    __shared__ float gred[4][E_];
    if (lane == 0)
        for (int e = 0; e < E_; e++) gred[wave][e] = acc[e];
    __syncthreads();
    if (tid == 0) {
        float lg[E_];
        float mxl = -FLT_MAX; int mi = 0;
        for (int e = 0; e < E_; e++)
            lg[e] = gred[0][e]+gred[1][e]+gred[2][e]+gred[3][e] + gbv[e];
        for (int e = 0; e < E_; e++)
            if (lg[e] > mxl) { mxl = lg[e]; mi = e; }
        float ssum = 0.f;
        for (int e = 0; e < E_; e++) ssum += expf(lg[e] - mxl);
        gi[row] = mi;
        gw[row] = 1.0f / ssum;
    }
}

__global__ void route_kernel(const int* __restrict__ gi,
                             int* __restrict__ offs, int* __restrict__ perm)
{
    __shared__ int cnt[E_], c2[E_], off[E_+1];
    const int tid = threadIdx.x;
    if (tid < E_) { cnt[tid] = 0; c2[tid] = 0; }
    __syncthreads();
    int e = gi[tid];
    atomicAdd(&cnt[e], 1);
    __syncthreads();
    if (tid == 0) {
        off[0] = 0;
        for (int i = 0; i < E_; i++) off[i+1] = off[i] + cnt[i];
        for (int i = 0; i <= E_; i++) offs[i] = off[i];
    }
    __syncthreads();
    int r = atomicAdd(&c2[e], 1);
    perm[off[e] + r] = tid;
}

__global__ void loss_kernel(const int* __restrict__ gi,
                            const float* __restrict__ gw, float* __restrict__ out)
{
    __shared__ float ss[E_], sc[E_];
    const int tid = threadIdx.x;
    if (tid < E_) { ss[tid] = 0.f; sc[tid] = 0.f; }
    __syncthreads();
    for (int t = tid; t < T_; t += 256) {
        int e = gi[t];
        atomicAdd(&ss[e], gw[t]);
        atomicAdd(&sc[e], 1.0f);
    }
    __syncthreads();
    if (tid == 0) {
        float loss = 0.f;
        for (int e = 0; e < E_; e++) {
            float u = ss[e] / (sc[e] + 1e-8f);
            float d = u - 0.125f;
            loss += d * d;
        }
        out[(size_t)T_ * D_] = loss;
    }
}

extern "C" void kernel_launch(void* const* d_in, const int* in_sizes, int n_in,
                              void* d_out, int out_size, void* d_ws, size_t ws_size,
                              hipStream_t stream)
{
    const float* x     = (const float*)d_in[0];
    const int*   ids   = (const int*)d_in[1];
    const float* ln1w  = (const float*)d_in[2];
    const float* ln1b  = (const float*)d_in[3];
    const float* qkvw  = (const float*)d_in[4];
    const float* qkvb  = (const float*)d_in[5];
    const float* aow   = (const float*)d_in[6];
    const float* aob   = (const float*)d_in[7];
    const float* ln2w  = (const float*)d_in[8];
    const float* ln2b  = (const float*)d_in[9];
    const float* gatew = (const float*)d_in[10];
    const float* gateb = (const float*)d_in[11];
    const float* fcw   = (const float*)d_in[12];
    const float* fcb   = (const float*)d_in[13];
    const float* eoutw = (const float*)d_in[14];
    const float* eoutb = (const float*)d_in[15];
    float* out = (float*)d_out;
    float* ws  = (float*)d_ws;

    short* hb    = (short*)(ws + WS_H);   // bf16 LN1 out; slot reused as SACC later
    float* sacc  = ws + WS_H;
    float* qkv   = ws + WS_QKV;
    short* attnb = (short*)(ws + WS_ATTN);
    float* x2    = ws + WS_X2;
    short* h2b   = (short*)(ws + WS_H2);
    short* abuf  = (short*)(ws + WS_A);
    float* gw    = ws + WS_GW;
    int*   gi    = (int*)(ws + WS_GI);
    int*   offs  = (int*)(ws + WS_OFFS);
    int*   perm  = (int*)(ws + WS_PERM);
    float* h12   = ws + WS_H12;           // 2 x (T,F2) split-K partials

    // 1. LN1 (bf16 out)
    ln_kernel<<<T_, 256, 0, stream>>>(x, ln1w, ln1b, hb);
    // 2. QKV projection: bias pre-fill + split-K=2 accumulating GEMM
    bias_fill<<<T_, 256, 0, stream>>>(qkvb, qkv, D3_);
    gemm_mfma_acc<<<dim3(D3_/64, 2, T_/128), 256, 0, stream>>>(
        hb, D_, qkvw, D3_, 0, nullptr, nullptr, qkv, D3_, D_, 2);
    // 3. RoPE
    rope_kernel<<<(T_*H_*32)/256, 256, 0, stream>>>(qkv);
    // 4. MFMA flash attention (bf16 out)
    flash_attn<<<dim3(T_/32, H_), 128, 0, stream>>>(qkv, ids, attnb);
    // 5. zero split-K accumulator
    hipMemsetAsync(sacc, 0, (size_t)T_*D_*sizeof(float), stream);
    // 6. attn output projection (split-K=4)
    gemm_mfma_acc<<<dim3(D_/64, 4, T_/128), 256, 0, stream>>>(
        attnb, D_, aow, D_, 0, nullptr, nullptr, sacc, D_, D_, 4);
    // 7. residual + bias
    ep_attn<<<T_, 256, 0, stream>>>(x, sacc, aob, x2);
    // 8. LN2 + gate (bf16 h2)
    ln2_gate_kernel<<<T_, 256, 0, stream>>>(x2, ln2w, ln2b, gatew, gateb, h2b, gi, gw);
    // 9. routing
    route_kernel<<<1, T_, 0, stream>>>(gi, offs, perm);
    // 10. expert fc: split-K=2, direct dual-buffer stores (no GLU fusion)
    gemm_fc_sk<<<dim3(F2_/64, 2*E_, T_/128), 256, 0, stream>>>(h2b, fcw, offs, perm, h12);
    // 10b. GLU epilogue (sum halves + bias + gelu), bf16 out
    glu_kernel<<<T_, 256, 0, stream>>>(h12, fcb, gi, abuf);
    // 11. re-zero accumulator
    hipMemsetAsync(sacc, 0, (size_t)T_*D_*sizeof(float), stream);
    // 12. expert out (split-K=8, routed)
    gemm_mfma_acc<<<dim3(D_/64, 8*E_, T_/128), 256, 0, stream>>>(
        abuf, F_, eoutw, D_, (long)F_*D_, offs, perm, sacc, D_, F_, 8);
    // 13. residual + gate scale + bias
    ep_moe<<<T_, 256, 0, stream>>>(x2, sacc, eoutb, gw, gi, out);
    // 14. aux loss
    loss_kernel<<<1, 256, 0, stream>>>(gi, gw, out);
}

// Round 12
// 573.925 us; speedup vs baseline: 1.0121x; 1.0121x over previous
//
#include <hip/hip_runtime.h>
#include <float.h>
#include <math.h>
#include <stdint.h>

#define T_ 1024
#define D_ 1024
#define H_ 16
#define HD_ 64
#define E_ 8
#define F_ 2560
#define D3_ 3072
#define F2_ 5120

// ---- workspace layout (float offsets) ----
#define WS_H    0u         // LN1 out (bf16); later reused as SACC (fp32 split-K accum)
#define WS_QKV  1048576u   // 3M   qkv (T,3D) fp32
#define WS_ATTN 4194304u   // attention out (T,D) bf16
#define WS_X2   5242880u   // x + attn proj (T,D) fp32
#define WS_H2   6291456u   // LN2 out (T,D) bf16
#define WS_A    7340032u   // gated activation (T,F) bf16
#define WS_GW   9961472u
#define WS_GI   9962496u
#define WS_OFFS 9963520u
#define WS_PERM 9963536u
#define WS_H12  10485760u  // 2 x (T,F2) fp32 split-K partial sums (84 MB total)

typedef short short8 __attribute__((ext_vector_type(8)));
typedef short short4v __attribute__((ext_vector_type(4)));
typedef __bf16 bf16x8 __attribute__((ext_vector_type(8)));
typedef float floatx4 __attribute__((ext_vector_type(4)));

union FragU { short8 s; bf16x8 b; };

__device__ __forceinline__ short f2bf(float f) {
    union { float f; uint32_t u; } a; a.f = f;
    uint32_t r = a.u + 0x7fffu + ((a.u >> 16) & 1u);
    return (short)(r >> 16);
}

__device__ __forceinline__ void cvt16(const float4& a0, const float4& a1,
                                      const float4& a2, const float4& a3,
                                      short8& c0, short8& c1) {
    c0[0]=f2bf(a0.x); c0[1]=f2bf(a0.y); c0[2]=f2bf(a0.z); c0[3]=f2bf(a0.w);
    c0[4]=f2bf(a1.x); c0[5]=f2bf(a1.y); c0[6]=f2bf(a1.z); c0[7]=f2bf(a1.w);
    c1[0]=f2bf(a2.x); c1[1]=f2bf(a2.y); c1[2]=f2bf(a2.z); c1[3]=f2bf(a2.w);
    c1[4]=f2bf(a3.x); c1[5]=f2bf(a3.y); c1[6]=f2bf(a3.z); c1[7]=f2bf(a3.w);
}

// ===================== MFMA GEMM cores =====================
// Tile: BM=128, BN=64, BK=32. 256 thr = 4 waves (2x2), wave tile 64x32.
// A operand is bf16 in global (pre-rounded by producers).
// B loads are k-major float4 (2 dwordx4/thread/step; 256B contiguous per row).
// K-loop unrolled x2 with two static register sets.
#define GEMM_IDS \
    const int tid  = threadIdx.x;                 \
    const int a_m  = tid >> 1;                    \
    const int a_kh = (tid & 1) * 16;              \
    const int lane = tid & 63, wave = tid >> 6;   \
    const int wm = wave & 1,  wn = wave >> 1;     \
    const int quad = lane >> 4, lm = lane & 15;   \
    const int bR = tid >> 4;                      \
    const int bC = (tid & 15) * 4;

// split-K accumulating GEMM (optionally token-routed): Cacc += A@B
// blockIdx.y: sk = y % nsk, e = y / nsk.  blockIdx.z = row block (mostly-dead dim last)
__global__ __launch_bounds__(256) void gemm_mfma_acc(
    const short* __restrict__ A, int lda,      // bf16 activations
    const float* __restrict__ B, int ldb, long sB,
    const int* __restrict__ offs, const int* __restrict__ perm,
    float* __restrict__ Cacc, int ldc, int K, int nsk)
{
    const int sk = blockIdx.y % nsk;
    const int e  = blockIdx.y / nsk;
    int off = 0, Ne = T_;
    if (offs) { off = offs[e]; Ne = offs[e+1] - off; }
    const int row0 = blockIdx.z * 128;
    if (row0 >= Ne) return;
    const int col0 = blockIdx.x * 64;
    B += (long)e * sB;

    __shared__ __align__(16) short As[4*128*8];
    __shared__ __align__(16) short Bs[64*40];
    __shared__ int toks[128];
    GEMM_IDS
    if (tid < 128) {
        int r = row0 + tid;
        toks[tid] = offs ? ((r < Ne) ? perm[off + r] : -1) : r;
    }
    __syncthreads();

    floatx4 acc[4][2];
    #pragma unroll
    for (int i=0;i<4;i++)
        #pragma unroll
        for (int j=0;j<2;j++) acc[i][j] = (floatx4){0.f,0.f,0.f,0.f};

    const int tokA = toks[a_m];
    const short* apx = (tokA >= 0) ? (A + (size_t)tokA * lda + a_kh) : nullptr;
    const float* bbase = B + col0 + bC;
    const int kcA = (tid & 1) * 2;
    const int Kp = K / nsk;
    const int koff = sk * Kp, kend = koff + Kp;

    short8 sA0 = {0,0,0,0,0,0,0,0}, sA1 = sA0, sB0 = sA0, sB1 = sA0;
    float4 bA0, bA1, bB0, bB1;
    if (apx) {
        sA0 = *(const short8*)(apx + koff);
        sA1 = *(const short8*)(apx + koff + 8);
        sB0 = *(const short8*)(apx + koff + 32);
        sB1 = *(const short8*)(apx + koff + 40);
    }
    bA0 = *(const float4*)(bbase + (size_t)(koff + bR) * ldb);
    bA1 = *(const float4*)(bbase + (size_t)(koff + bR + 16) * ldb);
    bB0 = *(const float4*)(bbase + (size_t)(koff + 32 + bR) * ldb);
    bB1 = *(const float4*)(bbase + (size_t)(koff + 32 + bR + 16) * ldb);

#define GA_STEP(S0,S1,BV0,BV1,kpre)                                       \
    __syncthreads();                                                      \
    {                                                                     \
        *(short8*)&As[((kcA  )*128 + a_m)*8] = S0;                        \
        *(short8*)&As[((kcA+1)*128 + a_m)*8] = S1;                        \
        Bs[(bC+0)*40 + bR]      = f2bf(BV0.x);                            \
        Bs[(bC+1)*40 + bR]      = f2bf(BV0.y);                            \
        Bs[(bC+2)*40 + bR]      = f2bf(BV0.z);                            \
        Bs[(bC+3)*40 + bR]      = f2bf(BV0.w);                            \
        Bs[(bC+0)*40 + bR + 16] = f2bf(BV1.x);                            \
        Bs[(bC+1)*40 + bR + 16] = f2bf(BV1.y);                            \
        Bs[(bC+2)*40 + bR + 16] = f2bf(BV1.z);                            \
        Bs[(bC+3)*40 + bR + 16] = f2bf(BV1.w);                            \
    }                                                                     \
    __syncthreads();                                                      \
    if ((kpre) < kend) {                                                  \
        if (apx) {                                                        \
            S0 = *(const short8*)(apx + (kpre));                          \
            S1 = *(const short8*)(apx + (kpre) + 8);                      \
        }                                                                 \
        BV0 = *(const float4*)(bbase + (size_t)((kpre) + bR) * ldb);      \
        BV1 = *(const float4*)(bbase + (size_t)((kpre) + bR + 16) * ldb); \
    }                                                                     \
    {                                                                     \
        FragU fa[4], fb[2];                                               \
        _Pragma("unroll")                                                 \
        for (int i=0;i<4;i++) fa[i].s = *(short8*)&As[(quad*128 + wm*64 + i*16 + lm)*8]; \
        _Pragma("unroll")                                                 \
        for (int j=0;j<2;j++) fb[j].s = *(short8*)&Bs[(wn*32 + j*16 + lm)*40 + quad*8];  \
        _Pragma("unroll")                                                 \
        for (int i=0;i<4;i++)                                             \
            _Pragma("unroll")                                             \
            for (int j=0;j<2;j++)                                         \
                acc[i][j] = __builtin_amdgcn_mfma_f32_16x16x32_bf16(fa[i].b, fb[j].b, acc[i][j], 0,0,0); \
    }

    for (int k0 = koff; k0 < kend; k0 += 64) {
        GA_STEP(sA0, sA1, bA0, bA1, k0 + 64)
        GA_STEP(sB0, sB1, bB0, bB1, k0 + 96)
    }
#undef GA_STEP

    #pragma unroll
    for (int i=0;i<4;i++)
        #pragma unroll
        for (int j=0;j<2;j++) {
            int col = col0 + wn*32 + j*16 + lm;
            #pragma unroll
            for (int r=0;r<4;r++) {
                int tk = toks[wm*64 + i*16 + quad*4 + r];
                if (tk >= 0) atomicAdd(&Cacc[(size_t)tk*ldc + col], acc[i][j][r]);
            }
        }
}

// MoE fc as split-K=2 GEMM, BN=64, direct (non-atomic) stores into two
// per-split fp32 buffers Cout[sk][tok][F2]. GLU applied by glu_kernel after.
__global__ __launch_bounds__(256) void gemm_fc_sk(
    const short* __restrict__ A, const float* __restrict__ B,
    const int* __restrict__ offs, const int* __restrict__ perm,
    float* __restrict__ Cout)
{
    const int sk = blockIdx.y & 1;
    const int e  = blockIdx.y >> 1;
    const int off = offs[e], Ne = offs[e+1] - off;
    const int row0 = blockIdx.z * 128;
    if (row0 >= Ne) return;
    const int col0 = blockIdx.x * 64;
    const float* Bw = B + (size_t)e * D_ * F2_;

    __shared__ __align__(16) short As[4*128*8];
    __shared__ __align__(16) short Bs[64*40];
    __shared__ int toks[128];
    GEMM_IDS
    if (tid < 128) {
        int r = row0 + tid;
        toks[tid] = (r < Ne) ? perm[off + r] : -1;
    }
    __syncthreads();

    floatx4 acc[4][2];
    #pragma unroll
    for (int i=0;i<4;i++)
        #pragma unroll
        for (int j=0;j<2;j++) acc[i][j] = (floatx4){0.f,0.f,0.f,0.f};

    const int tokA = toks[a_m];
    const short* apx = (tokA >= 0) ? (A + (size_t)tokA * D_ + a_kh) : nullptr;
    const float* bbase = Bw + col0 + bC;
    const int kcA = (tid & 1) * 2;
    const int koff = sk * (D_/2), kend = koff + (D_/2);

    short8 sA0 = {0,0,0,0,0,0,0,0}, sA1 = sA0, sB0 = sA0, sB1 = sA0;
    float4 bA0, bA1, bB0, bB1;
    if (apx) {
        sA0 = *(const short8*)(apx + koff);
        sA1 = *(const short8*)(apx + koff + 8);
        sB0 = *(const short8*)(apx + koff + 32);
        sB1 = *(const short8*)(apx + koff + 40);
    }
    bA0 = *(const float4*)(bbase + (size_t)(koff + bR) * F2_);
    bA1 = *(const float4*)(bbase + (size_t)(koff + bR + 16) * F2_);
    bB0 = *(const float4*)(bbase + (size_t)(koff + 32 + bR) * F2_);
    bB1 = *(const float4*)(bbase + (size_t)(koff + 32 + bR + 16) * F2_);

#define FC_STEP(S0,S1,BV0,BV1,kpre)                                       \
    __syncthreads();                                                      \
    {                                                                     \
        *(short8*)&As[((kcA  )*128 + a_m)*8] = S0;                        \
        *(short8*)&As[((kcA+1)*128 + a_m)*8] = S1;                        \
        Bs[(bC+0)*40 + bR]      = f2bf(BV0.x);                            \
        Bs[(bC+1)*40 + bR]      = f2bf(BV0.y);                            \
        Bs[(bC+2)*40 + bR]      = f2bf(BV0.z);                            \
        Bs[(bC+3)*40 + bR]      = f2bf(BV0.w);                            \
        Bs[(bC+0)*40 + bR + 16] = f2bf(BV1.x);                            \
        Bs[(bC+1)*40 + bR + 16] = f2bf(BV1.y);                            \
        Bs[(bC+2)*40 + bR + 16] = f2bf(BV1.z);                            \
        Bs[(bC+3)*40 + bR + 16] = f2bf(BV1.w);                            \
    }                                                                     \
    __syncthreads();                                                      \
    if ((kpre) < kend) {                                                  \
        if (apx) {                                                        \
            S0 = *(const short8*)(apx + (kpre));                          \
            S1 = *(const short8*)(apx + (kpre) + 8);                      \
        }                                                                 \
        BV0 = *(const float4*)(bbase + (size_t)((kpre) + bR) * F2_);      \
        BV1 = *(const float4*)(bbase + (size_t)((kpre) + bR + 16) * F2_); \
    }                                                                     \
    {                                                                     \
        FragU fa[4], fb[2];                                               \
        _Pragma("unroll")                                                 \
        for (int i=0;i<4;i++) fa[i].s = *(short8*)&As[(quad*128 + wm*64 + i*16 + lm)*8]; \
        _Pragma("unroll")                                                 \
        for (int j=0;j<2;j++) fb[j].s = *(short8*)&Bs[(wn*32 + j*16 + lm)*40 + quad*8];  \
        _Pragma("unroll")                                                 \
        for (int i=0;i<4;i++)                                             \
            _Pragma("unroll")                                             \
            for (int j=0;j<2;j++)                                         \
                acc[i][j] = __builtin_amdgcn_mfma_f32_16x16x32_bf16(fa[i].b, fb[j].b, acc[i][j], 0,0,0); \
    }

    for (int k0 = koff; k0 < kend; k0 += 64) {
        FC_STEP(sA0, sA1, bA0, bA1, k0 + 64)
        FC_STEP(sB0, sB1, bB0, bB1, k0 + 96)
    }
#undef FC_STEP

    #pragma unroll
    for (int i=0;i<4;i++)
        #pragma unroll
        for (int j=0;j<2;j++) {
            int col = col0 + wn*32 + j*16 + lm;
            #pragma unroll
            for (int r=0;r<4;r++) {
                int tk = toks[wm*64 + i*16 + quad*4 + r];
                if (tk >= 0)
                    Cout[((size_t)(sk*T_ + tk))*F2_ + col] = acc[i][j][r];
            }
        }
}

// GLU epilogue: sum the two split-K halves, add bias, x1 * gelu(x2), bf16 out.
__global__ __launch_bounds__(256) void glu_kernel(
    const float* __restrict__ h12, const float* __restrict__ fcb,
    const int* __restrict__ gi, short* __restrict__ aout)
{
    const int t = blockIdx.x, tid = threadIdx.x;
    const int e = gi[t];
    const float* p0 = h12 + (size_t)t * F2_;
    const float* p1 = h12 + (size_t)(T_ + t) * F2_;
    const float* fb = fcb + (size_t)e * F2_;
    for (int c = tid*4; c < F_; c += 1024) {
        float4 x0 = *(const float4*)(p0 + c);
        float4 x1 = *(const float4*)(p1 + c);
        float4 xb = *(const float4*)(fb + c);
        float4 g0 = *(const float4*)(p0 + F_ + c);
        float4 g1 = *(const float4*)(p1 + F_ + c);
        float4 gb = *(const float4*)(fb + F_ + c);
        float a1[4] = {x0.x+x1.x+xb.x, x0.y+x1.y+xb.y, x0.z+x1.z+xb.z, x0.w+x1.w+xb.w};
        float a2[4] = {g0.x+g1.x+gb.x, g0.y+g1.y+gb.y, g0.z+g1.z+gb.z, g0.w+g1.w+gb.w};
        short4v o;
        #pragma unroll
        for (int j=0;j<4;j++) {
            float g = a2[j] * 0.5f * (1.0f + erff(a2[j] * 0.70710678118654752f));
            o[j] = f2bf(a1[j] * g);
        }
        *(short4v*)(aout + (size_t)t*F_ + c) = o;
    }
}

// fill buf rows with a bias vector (pre-fill for split-K accumulation)
__global__ __launch_bounds__(256) void bias_fill(
    const float* __restrict__ bias, float* __restrict__ buf, int width)
{
    const int row = blockIdx.x, tid = threadIdx.x;
    for (int c = tid*4; c < width; c += 1024) {
        float4 b = *(const float4*)(bias + c);
        *(float4*)(buf + (size_t)row*width + c) = b;
    }
}

// ===================== MFMA flash attention =====================
__global__ __launch_bounds__(128) void flash_attn(
    const float* __restrict__ qkv, const int* __restrict__ ids,
    short* __restrict__ attnout)
{
    const int h  = blockIdx.y;
    const int q0 = blockIdx.x * 32;
    const int tid = threadIdx.x;
    const int lane = tid & 63, w = tid >> 6;
    const int quad = lane >> 4, lm = lane & 15;

    __shared__ __align__(16) short Qs[32*72];
    __shared__ __align__(16) short Ks[64*72];
    __shared__ __align__(16) short Vt[64*72];
    __shared__ __align__(16) short Ps[2][16*72];
    __shared__ int globf[32];

    {
        int row = tid >> 2, c = (tid & 3) * 16;
        const float* qp = qkv + (size_t)(q0 + row) * D3_ + h * HD_ + c;
        float4 f0 = *(const float4*)(qp);
        float4 f1 = *(const float4*)(qp + 4);
        float4 f2 = *(const float4*)(qp + 8);
        float4 f3 = *(const float4*)(qp + 12);
        short8 s0, s1;
        cvt16(f0, f1, f2, f3, s0, s1);
        *(short8*)&Qs[row*72 + c]     = s0;
        *(short8*)&Qs[row*72 + c + 8] = s1;
    }
    if (tid < 32) {
        int id = ids[q0 + tid];
        globf[tid] = (id >= 2 && id <= 7) ? 1 : 0;
    }
    __syncthreads();

    FragU QA[2];
    #pragma unroll
    for (int s = 0; s < 2; s++)
        QA[s].s = *(short8*)&Qs[(w*16 + lm)*72 + s*32 + quad*8];

    int any = 0;
    #pragma unroll
    for (int i = 0; i < 32; i++) any |= globf[i];
    const int nt = any ? (T_/64) : ((q0 + 31) >> 6) + 1;

    int gq[4]; int qidx[4];
    #pragma unroll
    for (int r = 0; r < 4; r++) {
        int ql = w*16 + quad*4 + r;
        qidx[r] = q0 + ql;
        gq[r] = globf[ql];
    }

    float mrow[4] = {-1e30f, -1e30f, -1e30f, -1e30f};
    float lrow[4] = {0.f, 0.f, 0.f, 0.f};
    floatx4 Oacc[4];
    #pragma unroll
    for (int n = 0; n < 4; n++) Oacc[n] = (floatx4){0.f, 0.f, 0.f, 0.f};

    for (int kt = 0; kt < nt; kt++) {
        __syncthreads();
        #pragma unroll
        for (int rep = 0; rep < 2; rep++) {
            int key = (tid >> 2) + rep*32;
            int c = (tid & 3) * 16;
            const float* kp = qkv + (size_t)(kt*64 + key) * D3_ + D_ + h*HD_ + c;
            float4 f0 = *(const float4*)(kp);
            float4 f1 = *(const float4*)(kp + 4);
            float4 f2 = *(const float4*)(kp + 8);
            float4 f3 = *(const float4*)(kp + 12);
            short8 s0, s1;
            cvt16(f0, f1, f2, f3, s0, s1);
            *(short8*)&Ks[key*72 + c]     = s0;
            *(short8*)&Ks[key*72 + c + 8] = s1;
        }
        #pragma unroll
        for (int rep = 0; rep < 8; rep++) {
            int lin = tid + rep*128;
            int key = lin >> 4;
            int c = (lin & 15) * 4;
            const float* vp = qkv + (size_t)(kt*64 + key) * D3_ + 2*D_ + h*HD_ + c;
            float4 f = *(const float4*)vp;
            Vt[(c+0)*72 + key] = f2bf(f.x);
            Vt[(c+1)*72 + key] = f2bf(f.y);
            Vt[(c+2)*72 + key] = f2bf(f.z);
            Vt[(c+3)*72 + key] = f2bf(f.w);
        }
        __syncthreads();

        floatx4 Sv[4];
        #pragma unroll
        for (int n = 0; n < 4; n++) {
            Sv[n] = (floatx4){0.f, 0.f, 0.f, 0.f};
            #pragma unroll
            for (int s = 0; s < 2; s++) {
                FragU KB;
                KB.s = *(short8*)&Ks[(n*16 + lm)*72 + s*32 + quad*8];
                Sv[n] = __builtin_amdgcn_mfma_f32_16x16x32_bf16(QA[s].b, KB.b, Sv[n], 0, 0, 0);
            }
        }
        #pragma unroll
        for (int n = 0; n < 4; n++) {
            int key = kt*64 + n*16 + lm;
            #pragma unroll
            for (int r = 0; r < 4; r++) {
                float v = Sv[n][r] * 0.125f;
                if (!gq[r] && key > qidx[r]) v = -1e30f;
                Sv[n][r] = v;
            }
        }
        float mnew[4], alpha[4], tsum[4];
        #pragma unroll
        for (int r = 0; r < 4; r++) {
            float tm = fmaxf(fmaxf(Sv[0][r], Sv[1][r]), fmaxf(Sv[2][r], Sv[3][r]));
            #pragma unroll
            for (int x = 1; x < 16; x <<= 1) tm = fmaxf(tm, __shfl_xor(tm, x));
            mnew[r] = fmaxf(mrow[r], tm);
            alpha[r] = __expf(mrow[r] - mnew[r]);
            mrow[r] = mnew[r];
            tsum[r] = 0.f;
        }
        #pragma unroll
        for (int n = 0; n < 4; n++) {
            #pragma unroll
            for (int r = 0; r < 4; r++) {
                float p = __expf(Sv[n][r] - mnew[r]);
                tsum[r] += p;
                Ps[w][(quad*4 + r)*72 + n*16 + lm] = f2bf(p);
            }
        }
        #pragma unroll
        for (int r = 0; r < 4; r++) {
            #pragma unroll
            for (int x = 1; x < 16; x <<= 1) tsum[r] += __shfl_xor(tsum[r], x);
            lrow[r] = lrow[r] * alpha[r] + tsum[r];
        }
        #pragma unroll
        for (int n = 0; n < 4; n++)
            #pragma unroll
            for (int r = 0; r < 4; r++) Oacc[n][r] *= alpha[r];

        #pragma unroll
        for (int s = 0; s < 2; s++) {
            FragU PA;
            PA.s = *(short8*)&Ps[w][lm*72 + s*32 + quad*8];
            #pragma unroll
            for (int n = 0; n < 4; n++) {
                FragU VB;
                VB.s = *(short8*)&Vt[(n*16 + lm)*72 + s*32 + quad*8];
                Oacc[n] = __builtin_amdgcn_mfma_f32_16x16x32_bf16(PA.b, VB.b, Oacc[n], 0, 0, 0);
            }
        }
    }

    #pragma unroll
    for (int n = 0; n < 4; n++)
        #pragma unroll
        for (int r = 0; r < 4; r++) {
            float o = Oacc[n][r] / lrow[r];
            attnout[(size_t)qidx[r]*D_ + h*HD_ + n*16 + lm] = f2bf(o);
        }
}

// ===================== epilogues =====================
__global__ __launch_bounds__(256) void ep_attn(
    const float* __restrict__ x, const float* __restrict__ sacc,
    const float* __restrict__ aob, float* __restrict__ x2)
{
    int row = blockIdx.x, tid = threadIdx.x;
    float4 xv = ((const float4*)(x + (size_t)row*D_))[tid];
    float4 sv = ((const float4*)(sacc + (size_t)row*D_))[tid];
    float4 bv = ((const float4*)aob)[tid];
    float4 o;
    o.x = xv.x + sv.x + bv.x; o.y = xv.y + sv.y + bv.y;
    o.z = xv.z + sv.z + bv.z; o.w = xv.w + sv.w + bv.w;
    ((float4*)(x2 + (size_t)row*D_))[tid] = o;
}

__global__ __launch_bounds__(256) void ep_moe(
    const float* __restrict__ x2, const float* __restrict__ sacc,
    const float* __restrict__ eob, const float* __restrict__ gw,
    const int* __restrict__ gi, float* __restrict__ out)
{
    int row = blockIdx.x, tid = threadIdx.x;
    float g = gw[row];
    int e = gi[row];
    float4 xv = ((const float4*)(x2 + (size_t)row*D_))[tid];
    float4 sv = ((const float4*)(sacc + (size_t)row*D_))[tid];
    float4 bv = ((const float4*)(eob + (size_t)e*D_))[tid];
    float4 o;
    o.x = xv.x + g*(sv.x + bv.x); o.y = xv.y + g*(sv.y + bv.y);
    o.z = xv.z + g*(sv.z + bv.z); o.w = xv.w + g*(sv.w + bv.w);
    ((float4*)(out + (size_t)row*D_))[tid] = o;
}

// ===================== small kernels =====================
__global__ __launch_bounds__(256) void ln_kernel(
    const float* __restrict__ x, const float* __restrict__ w,
    const float* __restrict__ b, short* __restrict__ out)   // bf16 out
{
    const int row = blockIdx.x, tid = threadIdx.x;
    const int lane = tid & 63, wave = tid >> 6;
    float4 v = ((const float4*)(x + (size_t)row * D_))[tid];
    float s  = v.x + v.y + v.z + v.w;
    float sq = v.x*v.x + v.y*v.y + v.z*v.z + v.w*v.w;
    #pragma unroll
    for (int off = 32; off; off >>= 1) {
        s  += __shfl_down(s, off);
        sq += __shfl_down(sq, off);
    }
    __shared__ float rs[4], rq[4], mv[2];
    if (lane == 0) { rs[wave] = s; rq[wave] = sq; }
    __syncthreads();
    if (tid == 0) {
        float ts = rs[0]+rs[1]+rs[2]+rs[3];
        float tq = rq[0]+rq[1]+rq[2]+rq[3];
        float mean = ts * (1.0f / D_);
        float var  = tq * (1.0f / D_) - mean*mean;
        mv[0] = mean; mv[1] = rsqrtf(var + 1e-5f);
    }
    __syncthreads();
    float mean = mv[0], rstd = mv[1];
    float4 wv = ((const float4*)w)[tid];
    float4 bv = ((const float4*)b)[tid];
    short4v o;
    o[0] = f2bf((v.x-mean)*rstd*wv.x + bv.x);
    o[1] = f2bf((v.y-mean)*rstd*wv.y + bv.y);
    o[2] = f2bf((v.z-mean)*rstd*wv.z + bv.z);
    o[3] = f2bf((v.w-mean)*rstd*wv.w + bv.w);
    ((short4v*)(out + (size_t)row * D_))[tid] = o;
}

__global__ __launch_bounds__(256) void rope_kernel(float* __restrict__ qkv)
{
    int gid = blockIdx.x * 256 + threadIdx.x;
    int t = gid >> 9;
    int r = gid & 511;
    int h = r >> 5;
    int d = r & 31;
    float inv = exp2f((float)d * -0.4152410118609203f);
    float fr = (float)t * inv;
    float s, c;
    sincosf(fr, &s, &c);
    float* base = qkv + (size_t)t*D3_ + h*HD_ + d;
    float q1 = base[0], q2 = base[32];
    base[0]  = q1*c - q2*s;
    base[32] = q1*s + q2*c;
    float* kb = base + D_;
    float k1 = kb[0], k2 = kb[32];
    kb[0]  = k1*c - k2*s;
    kb[32] = k1*s + k2*c;
}

__global__ __launch_bounds__(256) void ln2_gate_kernel(
    const float* __restrict__ x2, const float* __restrict__ w,
    const float* __restrict__ b, const float* __restrict__ gwm,
    const float* __restrict__ gbv, short* __restrict__ h2,   // bf16 out
    int* __restrict__ gi, float* __restrict__ gw)
{
    const int row = blockIdx.x, tid = threadIdx.x;
    const int lane = tid & 63, wave = tid >> 6;
    float4 v = ((const float4*)(x2 + (size_t)row * D_))[tid];
    float s  = v.x + v.y + v.z + v.w;
    float sq = v.x*v.x + v.y*v.y + v.z*v.z + v.w*v.w;
    #pragma unroll
    for (int off = 32; off; off >>= 1) {
        s  += __shfl_down(s, off);
        sq += __shfl_down(sq, off);
    }
    __shared__ float rs[4], rq[4], mv[2];
    if (lane == 0) { rs[wave] = s; rq[wave] = sq; }
    __syncthreads();
    if (tid == 0) {
        float ts = rs[0]+rs[1]+rs[2]+rs[3];
        float tq = rq[0]+rq[1]+rq[2]+rq[3];
        float mean = ts * (1.0f / D_);
        float var  = tq * (1.0f / D_) - mean*mean;
        mv[0] = mean; mv[1] = rsqrtf(var + 1e-5f);
    }
    __syncthreads();
    float mean = mv[0], rstd = mv[1];
    float4 wv = ((const float4*)w)[tid];
    float4 bv = ((const float4*)b)[tid];
    float hv[4];
    hv[0] = (v.x-mean)*rstd*wv.x + bv.x;
    hv[1] = (v.y-mean)*rstd*wv.y + bv.y;
    hv[2] = (v.z-mean)*rstd*wv.z + bv.z;
    hv[3] = (v.w-mean)*rstd*wv.w + bv.w;
    short4v o;
    o[0]=f2bf(hv[0]); o[1]=f2bf(hv[1]); o[2]=f2bf(hv[2]); o[3]=f2bf(hv[3]);
    ((short4v*)(h2 + (size_t)row * D_))[tid] = o;

    float acc[E_] = {};
    int c = tid * 4;
    #pragma unroll
    for (int j = 0; j < 4; j++) {
        const float* gr = gwm + (size_t)(c+j) * E_;
        #pragma unroll
        for (int e = 0; e < E_; e++) acc[e] += hv[j] * gr[e];
    }
    #pragma unroll
    for (int off = 32; off; off >>= 1)
        #pragma unroll
        for (int e = 0; e < E_; e++) acc[e] += __shfl_down(acc[e], off);
    __shared__ float gred[4][E_];
    if (lane == 0)
        for (int e = 0; e < E_; e++) gred[wave][e] = acc[e];
    __syncthreads();
    if (tid == 0) {
        float lg[E_];
        float mxl = -FLT_MAX; int mi = 0;
        for (int e = 0; e < E_; e++)
            lg[e] = gred[0][e]+gred[1][e]+gred[2][e]+gred[3][e] + gbv[e];
        for (int e = 0; e < E_; e++)
            if (lg[e] > mxl) { mxl = lg[e]; mi = e; }
        float ssum = 0.f;
        for (int e = 0; e < E_; e++) ssum += expf(lg[e] - mxl);
        gi[row] = mi;
        gw[row] = 1.0f / ssum;
    }
}

__global__ void route_kernel(const int* __restrict__ gi,
                             int* __restrict__ offs, int* __restrict__ perm)
{
    __shared__ int cnt[E_], c2[E_], off[E_+1];
    const int tid = threadIdx.x;
    if (tid < E_) { cnt[tid] = 0; c2[tid] = 0; }
    __syncthreads();
    int e = gi[tid];
    atomicAdd(&cnt[e], 1);
    __syncthreads();
    if (tid == 0) {
        off[0] = 0;
        for (int i = 0; i < E_; i++) off[i+1] = off[i] + cnt[i];
        for (int i = 0; i <= E_; i++) offs[i] = off[i];
    }
    __syncthreads();
    int r = atomicAdd(&c2[e], 1);
    perm[off[e] + r] = tid;
}

__global__ void loss_kernel(const int* __restrict__ gi,
                            const float* __restrict__ gw, float* __restrict__ out)
{
    __shared__ float ss[E_], sc[E_];
    const int tid = threadIdx.x;
    if (tid < E_) { ss[tid] = 0.f; sc[tid] = 0.f; }
    __syncthreads();
    for (int t = tid; t < T_; t += 256) {
        int e = gi[t];
        atomicAdd(&ss[e], gw[t]);
        atomicAdd(&sc[e], 1.0f);
    }
    __syncthreads();
    if (tid == 0) {
        float loss = 0.f;
        for (int e = 0; e < E_; e++) {
            float u = ss[e] / (sc[e] + 1e-8f);
            float d = u - 0.125f;
            loss += d * d;
        }
        out[(size_t)T_ * D_] = loss;
    }
}

extern "C" void kernel_launch(void* const* d_in, const int* in_sizes, int n_in,
                              void* d_out, int out_size, void* d_ws, size_t ws_size,
                              hipStream_t stream)
{
    const float* x     = (const float*)d_in[0];
    const int*   ids   = (const int*)d_in[1];
    const float* ln1w  = (const float*)d_in[2];
    const float* ln1b  = (const float*)d_in[3];
    const float* qkvw  = (const float*)d_in[4];
    const float* qkvb  = (const float*)d_in[5];
    const float* aow   = (const float*)d_in[6];
    const float* aob   = (const float*)d_in[7];
    const float* ln2w  = (const float*)d_in[8];
    const float* ln2b  = (const float*)d_in[9];
    const float* gatew = (const float*)d_in[10];
    const float* gateb = (const float*)d_in[11];
    const float* fcw   = (const float*)d_in[12];
    const float* fcb   = (const float*)d_in[13];
    const float* eoutw = (const float*)d_in[14];
    const float* eoutb = (const float*)d_in[15];
    float* out = (float*)d_out;
    float* ws  = (float*)d_ws;

    short* hb    = (short*)(ws + WS_H);   // bf16 LN1 out; slot reused as SACC later
    float* sacc  = ws + WS_H;
    float* qkv   = ws + WS_QKV;
    short* attnb = (short*)(ws + WS_ATTN);
    float* x2    = ws + WS_X2;
    short* h2b   = (short*)(ws + WS_H2);
    short* abuf  = (short*)(ws + WS_A);
    float* gw    = ws + WS_GW;
    int*   gi    = (int*)(ws + WS_GI);
    int*   offs  = (int*)(ws + WS_OFFS);
    int*   perm  = (int*)(ws + WS_PERM);
    float* h12   = ws + WS_H12;           // 2 x (T,F2) split-K partials

    // 1. LN1 (bf16 out)
    ln_kernel<<<T_, 256, 0, stream>>>(x, ln1w, ln1b, hb);
    // 2. QKV projection: bias pre-fill + split-K=2 accumulating GEMM
    bias_fill<<<T_, 256, 0, stream>>>(qkvb, qkv, D3_);
    gemm_mfma_acc<<<dim3(D3_/64, 2, T_/128), 256, 0, stream>>>(
        hb, D_, qkvw, D3_, 0, nullptr, nullptr, qkv, D3_, D_, 2);
    // 3. RoPE
    rope_kernel<<<(T_*H_*32)/256, 256, 0, stream>>>(qkv);
    // 4. MFMA flash attention (bf16 out)
    flash_attn<<<dim3(T_/32, H_), 128, 0, stream>>>(qkv, ids, attnb);
    // 5. zero split-K accumulator
    hipMemsetAsync(sacc, 0, (size_t)T_*D_*sizeof(float), stream);
    // 6. attn output projection (split-K=4)
    gemm_mfma_acc<<<dim3(D_/64, 4, T_/128), 256, 0, stream>>>(
        attnb, D_, aow, D_, 0, nullptr, nullptr, sacc, D_, D_, 4);
    // 7. residual + bias
    ep_attn<<<T_, 256, 0, stream>>>(x, sacc, aob, x2);
    // 8. LN2 + gate (bf16 h2)
    ln2_gate_kernel<<<T_, 256, 0, stream>>>(x2, ln2w, ln2b, gatew, gateb, h2b, gi, gw);
    // 9. routing
    route_kernel<<<1, T_, 0, stream>>>(gi, offs, perm);
    // 10. expert fc: split-K=2, direct dual-buffer stores (no GLU fusion)
    gemm_fc_sk<<<dim3(F2_/64, 2*E_, T_/128), 256, 0, stream>>>(h2b, fcw, offs, perm, h12);
    // 10b. GLU epilogue (sum halves + bias + gelu), bf16 out
    glu_kernel<<<T_, 256, 0, stream>>>(h12, fcb, gi, abuf);
    // 11. re-zero accumulator
    hipMemsetAsync(sacc, 0, (size_t)T_*D_*sizeof(float), stream);
    // 12. expert out (split-K=8, routed)
    gemm_mfma_acc<<<dim3(D_/64, 8*E_, T_/128), 256, 0, stream>>>(
        abuf, F_, eoutw, D_, (long)F_*D_, offs, perm, sacc, D_, F_, 8);
    // 13. residual + gate scale + bias
    ep_moe<<<T_, 256, 0, stream>>>(x2, sacc, eoutb, gw, gi, out);
    // 14. aux loss
    loss_kernel<<<1, 256, 0, stream>>>(gi, gw, out);
}

// Round 13
// 559.354 us; speedup vs baseline: 1.0384x; 1.0261x over previous
//
#include <hip/hip_runtime.h>
#include <float.h>
#include <math.h>
#include <stdint.h>

#define T_ 1024
#define D_ 1024
#define H_ 16
#define HD_ 64
#define E_ 8
#define F_ 2560
#define D3_ 3072
#define F2_ 5120

// ---- workspace layout (float offsets) ----
#define WS_H    0u         // LN1 out (bf16); later reused as SACC (fp32 split-K accum)
#define WS_QKV  1048576u   // 3M   qkv (T,3D) fp32
#define WS_ATTN 4194304u   // attention out (T,D) bf16
#define WS_X2   5242880u   // x + attn proj (T,D) fp32
#define WS_H2   6291456u   // LN2 out (T,D) bf16
#define WS_A    7340032u   // gated activation (T,F) bf16
#define WS_GW   9961472u
#define WS_GI   9962496u
#define WS_OFFS 9963520u
#define WS_PERM 9963536u
#define WS_H12  10485760u  // 2 x (T,F2) fp32 split-K partial sums (84 MB total)

typedef short short8 __attribute__((ext_vector_type(8)));
typedef short short4v __attribute__((ext_vector_type(4)));
typedef __bf16 bf16x8 __attribute__((ext_vector_type(8)));
typedef float floatx4 __attribute__((ext_vector_type(4)));

union FragU { short8 s; bf16x8 b; };

__device__ __forceinline__ short f2bf(float f) {
    union { float f; uint32_t u; } a; a.f = f;
    uint32_t r = a.u + 0x7fffu + ((a.u >> 16) & 1u);
    return (short)(r >> 16);
}

__device__ __forceinline__ void cvt16(const float4& a0, const float4& a1,
                                      const float4& a2, const float4& a3,
                                      short8& c0, short8& c1) {
    c0[0]=f2bf(a0.x); c0[1]=f2bf(a0.y); c0[2]=f2bf(a0.z); c0[3]=f2bf(a0.w);
    c0[4]=f2bf(a1.x); c0[5]=f2bf(a1.y); c0[6]=f2bf(a1.z); c0[7]=f2bf(a1.w);
    c1[0]=f2bf(a2.x); c1[1]=f2bf(a2.y); c1[2]=f2bf(a2.z); c1[3]=f2bf(a2.w);
    c1[4]=f2bf(a3.x); c1[5]=f2bf(a3.y); c1[6]=f2bf(a3.z); c1[7]=f2bf(a3.w);
}

// ===================== MFMA GEMM cores =====================
// Tile: BM=128, BN=64, BK=32. 256 thr = 4 waves (2x2), wave tile 64x32.
// A operand is bf16 in global (pre-rounded by producers).
// B loads are k-major float4.  4-deep register pipeline: K-loop unrolled x4,
// each register set is prefetched 4 sub-steps (128 K) before consumption,
// giving loads ~2x HBM latency of cover.  Requires Kp % 128 == 0.
#define GEMM_IDS \
    const int tid  = threadIdx.x;                 \
    const int a_m  = tid >> 1;                    \
    const int a_kh = (tid & 1) * 16;              \
    const int lane = tid & 63, wave = tid >> 6;   \
    const int wm = wave & 1,  wn = wave >> 1;     \
    const int quad = lane >> 4, lm = lane & 15;   \
    const int bR = tid >> 4;                      \
    const int bC = (tid & 15) * 4;

// split-K accumulating GEMM (optionally token-routed): Cacc += A@B
// blockIdx.y: sk = y % nsk, e = y / nsk.  blockIdx.z = row block (mostly-dead dim last)
__global__ __launch_bounds__(256) void gemm_mfma_acc(
    const short* __restrict__ A, int lda,      // bf16 activations
    const float* __restrict__ B, int ldb, long sB,
    const int* __restrict__ offs, const int* __restrict__ perm,
    float* __restrict__ Cacc, int ldc, int K, int nsk)
{
    const int sk = blockIdx.y % nsk;
    const int e  = blockIdx.y / nsk;
    int off = 0, Ne = T_;
    if (offs) { off = offs[e]; Ne = offs[e+1] - off; }
    const int row0 = blockIdx.z * 128;
    if (row0 >= Ne) return;
    const int col0 = blockIdx.x * 64;
    B += (long)e * sB;

    __shared__ __align__(16) short As[4*128*8];
    __shared__ __align__(16) short Bs[64*40];
    __shared__ int toks[128];
    GEMM_IDS
    if (tid < 128) {
        int r = row0 + tid;
        toks[tid] = offs ? ((r < Ne) ? perm[off + r] : -1) : r;
    }
    __syncthreads();

    floatx4 acc[4][2];
    #pragma unroll
    for (int i=0;i<4;i++)
        #pragma unroll
        for (int j=0;j<2;j++) acc[i][j] = (floatx4){0.f,0.f,0.f,0.f};

    const int tokA = toks[a_m];
    const short* apx = (tokA >= 0) ? (A + (size_t)tokA * lda + a_kh) : nullptr;
    const float* bbase = B + col0 + bC;
    const int kcA = (tid & 1) * 2;
    const int Kp = K / nsk;
    const int koff = sk * Kp, kend = koff + Kp;

    short8 zz = {0,0,0,0,0,0,0,0};
    short8 a0l=zz,a0h=zz,a1l=zz,a1h=zz,a2l=zz,a2h=zz,a3l=zz,a3h=zz;
    float4 b0a,b0b,b1a,b1b,b2a,b2b,b3a,b3b;
    if (apx) {
        a0l = *(const short8*)(apx + koff);      a0h = *(const short8*)(apx + koff + 8);
        a1l = *(const short8*)(apx + koff + 32); a1h = *(const short8*)(apx + koff + 40);
        a2l = *(const short8*)(apx + koff + 64); a2h = *(const short8*)(apx + koff + 72);
        a3l = *(const short8*)(apx + koff + 96); a3h = *(const short8*)(apx + koff + 104);
    }
    b0a = *(const float4*)(bbase + (size_t)(koff      + bR) * ldb);
    b0b = *(const float4*)(bbase + (size_t)(koff      + bR + 16) * ldb);
    b1a = *(const float4*)(bbase + (size_t)(koff + 32 + bR) * ldb);
    b1b = *(const float4*)(bbase + (size_t)(koff + 32 + bR + 16) * ldb);
    b2a = *(const float4*)(bbase + (size_t)(koff + 64 + bR) * ldb);
    b2b = *(const float4*)(bbase + (size_t)(koff + 64 + bR + 16) * ldb);
    b3a = *(const float4*)(bbase + (size_t)(koff + 96 + bR) * ldb);
    b3b = *(const float4*)(bbase + (size_t)(koff + 96 + bR + 16) * ldb);

#define GA_STEP(AL,AH,BV0,BV1,kpre)                                       \
    __syncthreads();                                                      \
    {                                                                     \
        *(short8*)&As[((kcA  )*128 + a_m)*8] = AL;                        \
        *(short8*)&As[((kcA+1)*128 + a_m)*8] = AH;                        \
        Bs[(bC+0)*40 + bR]      = f2bf(BV0.x);                            \
        Bs[(bC+1)*40 + bR]      = f2bf(BV0.y);                            \
        Bs[(bC+2)*40 + bR]      = f2bf(BV0.z);                            \
        Bs[(bC+3)*40 + bR]      = f2bf(BV0.w);                            \
        Bs[(bC+0)*40 + bR + 16] = f2bf(BV1.x);                            \
        Bs[(bC+1)*40 + bR + 16] = f2bf(BV1.y);                            \
        Bs[(bC+2)*40 + bR + 16] = f2bf(BV1.z);                            \
        Bs[(bC+3)*40 + bR + 16] = f2bf(BV1.w);                            \
    }                                                                     \
    __syncthreads();                                                      \
    if ((kpre) < kend) {                                                  \
        if (apx) {                                                        \
            AL = *(const short8*)(apx + (kpre));                          \
            AH = *(const short8*)(apx + (kpre) + 8);                      \
        }                                                                 \
        BV0 = *(const float4*)(bbase + (size_t)((kpre) + bR) * ldb);      \
        BV1 = *(const float4*)(bbase + (size_t)((kpre) + bR + 16) * ldb); \
    }                                                                     \
    {                                                                     \
        FragU fa[4], fb[2];                                               \
        _Pragma("unroll")                                                 \
        for (int i=0;i<4;i++) fa[i].s = *(short8*)&As[(quad*128 + wm*64 + i*16 + lm)*8]; \
        _Pragma("unroll")                                                 \
        for (int j=0;j<2;j++) fb[j].s = *(short8*)&Bs[(wn*32 + j*16 + lm)*40 + quad*8];  \
        _Pragma("unroll")                                                 \
        for (int i=0;i<4;i++)                                             \
            _Pragma("unroll")                                             \
            for (int j=0;j<2;j++)                                         \
                acc[i][j] = __builtin_amdgcn_mfma_f32_16x16x32_bf16(fa[i].b, fb[j].b, acc[i][j], 0,0,0); \
    }

    for (int k0 = koff; k0 < kend; k0 += 128) {
        GA_STEP(a0l,a0h,b0a,b0b, k0 + 128)
        GA_STEP(a1l,a1h,b1a,b1b, k0 + 160)
        GA_STEP(a2l,a2h,b2a,b2b, k0 + 192)
        GA_STEP(a3l,a3h,b3a,b3b, k0 + 224)
    }
#undef GA_STEP

    #pragma unroll
    for (int i=0;i<4;i++)
        #pragma unroll
        for (int j=0;j<2;j++) {
            int col = col0 + wn*32 + j*16 + lm;
            #pragma unroll
            for (int r=0;r<4;r++) {
                int tk = toks[wm*64 + i*16 + quad*4 + r];
                if (tk >= 0) atomicAdd(&Cacc[(size_t)tk*ldc + col], acc[i][j][r]);
            }
        }
}

// MoE fc as split-K=2 GEMM, BN=64, direct (non-atomic) stores into two
// per-split fp32 buffers Cout[sk][tok][F2]. GLU applied by glu_kernel after.
__global__ __launch_bounds__(256) void gemm_fc_sk(
    const short* __restrict__ A, const float* __restrict__ B,
    const int* __restrict__ offs, const int* __restrict__ perm,
    float* __restrict__ Cout)
{
    const int sk = blockIdx.y & 1;
    const int e  = blockIdx.y >> 1;
    const int off = offs[e], Ne = offs[e+1] - off;
    const int row0 = blockIdx.z * 128;
    if (row0 >= Ne) return;
    const int col0 = blockIdx.x * 64;
    const float* Bw = B + (size_t)e * D_ * F2_;

    __shared__ __align__(16) short As[4*128*8];
    __shared__ __align__(16) short Bs[64*40];
    __shared__ int toks[128];
    GEMM_IDS
    if (tid < 128) {
        int r = row0 + tid;
        toks[tid] = (r < Ne) ? perm[off + r] : -1;
    }
    __syncthreads();

    floatx4 acc[4][2];
    #pragma unroll
    for (int i=0;i<4;i++)
        #pragma unroll
        for (int j=0;j<2;j++) acc[i][j] = (floatx4){0.f,0.f,0.f,0.f};

    const int tokA = toks[a_m];
    const short* apx = (tokA >= 0) ? (A + (size_t)tokA * D_ + a_kh) : nullptr;
    const float* bbase = Bw + col0 + bC;
    const int kcA = (tid & 1) * 2;
    const int koff = sk * (D_/2), kend = koff + (D_/2);

    short8 zz = {0,0,0,0,0,0,0,0};
    short8 a0l=zz,a0h=zz,a1l=zz,a1h=zz,a2l=zz,a2h=zz,a3l=zz,a3h=zz;
    float4 b0a,b0b,b1a,b1b,b2a,b2b,b3a,b3b;
    if (apx) {
        a0l = *(const short8*)(apx + koff);      a0h = *(const short8*)(apx + koff + 8);
        a1l = *(const short8*)(apx + koff + 32); a1h = *(const short8*)(apx + koff + 40);
        a2l = *(const short8*)(apx + koff + 64); a2h = *(const short8*)(apx + koff + 72);
        a3l = *(const short8*)(apx + koff + 96); a3h = *(const short8*)(apx + koff + 104);
    }
    b0a = *(const float4*)(bbase + (size_t)(koff      + bR) * F2_);
    b0b = *(const float4*)(bbase + (size_t)(koff      + bR + 16) * F2_);
    b1a = *(const float4*)(bbase + (size_t)(koff + 32 + bR) * F2_);
    b1b = *(const float4*)(bbase + (size_t)(koff + 32 + bR + 16) * F2_);
    b2a = *(const float4*)(bbase + (size_t)(koff + 64 + bR) * F2_);
    b2b = *(const float4*)(bbase + (size_t)(koff + 64 + bR + 16) * F2_);
    b3a = *(const float4*)(bbase + (size_t)(koff + 96 + bR) * F2_);
    b3b = *(const float4*)(bbase + (size_t)(koff + 96 + bR + 16) * F2_);

#define FC_STEP(AL,AH,BV0,BV1,kpre)                                       \
    __syncthreads();                                                      \
    {                                                                     \
        *(short8*)&As[((kcA  )*128 + a_m)*8] = AL;                        \
        *(short8*)&As[((kcA+1)*128 + a_m)*8] = AH;                        \
        Bs[(bC+0)*40 + bR]      = f2bf(BV0.x);                            \
        Bs[(bC+1)*40 + bR]      = f2bf(BV0.y);                            \
        Bs[(bC+2)*40 + bR]      = f2bf(BV0.z);                            \
        Bs[(bC+3)*40 + bR]      = f2bf(BV0.w);                            \
        Bs[(bC+0)*40 + bR + 16] = f2bf(BV1.x);                            \
        Bs[(bC+1)*40 + bR + 16] = f2bf(BV1.y);                            \
        Bs[(bC+2)*40 + bR + 16] = f2bf(BV1.z);                            \
        Bs[(bC+3)*40 + bR + 16] = f2bf(BV1.w);                            \
    }                                                                     \
    __syncthreads();                                                      \
    if ((kpre) < kend) {                                                  \
        if (apx) {                                                        \
            AL = *(const short8*)(apx + (kpre));                          \
            AH = *(const short8*)(apx + (kpre) + 8);                      \
        }                                                                 \
        BV0 = *(const float4*)(bbase + (size_t)((kpre) + bR) * F2_);      \
        BV1 = *(const float4*)(bbase + (size_t)((kpre) + bR + 16) * F2_); \
    }                                                                     \
    {                                                                     \
        FragU fa[4], fb[2];                                               \
        _Pragma("unroll")                                                 \
        for (int i=0;i<4;i++) fa[i].s = *(short8*)&As[(quad*128 + wm*64 + i*16 + lm)*8]; \
        _Pragma("unroll")                                                 \
        for (int j=0;j<2;j++) fb[j].s = *(short8*)&Bs[(wn*32 + j*16 + lm)*40 + quad*8];  \
        _Pragma("unroll")                                                 \
        for (int i=0;i<4;i++)                                             \
            _Pragma("unroll")                                             \
            for (int j=0;j<2;j++)                                         \
                acc[i][j] = __builtin_amdgcn_mfma_f32_16x16x32_bf16(fa[i].b, fb[j].b, acc[i][j], 0,0,0); \
    }

    for (int k0 = koff; k0 < kend; k0 += 128) {
        FC_STEP(a0l,a0h,b0a,b0b, k0 + 128)
        FC_STEP(a1l,a1h,b1a,b1b, k0 + 160)
        FC_STEP(a2l,a2h,b2a,b2b, k0 + 192)
        FC_STEP(a3l,a3h,b3a,b3b, k0 + 224)
    }
#undef FC_STEP

    #pragma unroll
    for (int i=0;i<4;i++)
        #pragma unroll
        for (int j=0;j<2;j++) {
            int col = col0 + wn*32 + j*16 + lm;
            #pragma unroll
            for (int r=0;r<4;r++) {
                int tk = toks[wm*64 + i*16 + quad*4 + r];
                if (tk >= 0)
                    Cout[((size_t)(sk*T_ + tk))*F2_ + col] = acc[i][j][r];
            }
        }
}

// GLU epilogue: sum the two split-K halves, add bias, x1 * gelu(x2), bf16 out.
__global__ __launch_bounds__(256) void glu_kernel(
    const float* __restrict__ h12, const float* __restrict__ fcb,
    const int* __restrict__ gi, short* __restrict__ aout)
{
    const int t = blockIdx.x, tid = threadIdx.x;
    const int e = gi[t];
    const float* p0 = h12 + (size_t)t * F2_;
    const float* p1 = h12 + (size_t)(T_ + t) * F2_;
    const float* fb = fcb + (size_t)e * F2_;
    for (int c = tid*4; c < F_; c += 1024) {
        float4 x0 = *(const float4*)(p0 + c);
        float4 x1 = *(const float4*)(p1 + c);
        float4 xb = *(const float4*)(fb + c);
        float4 g0 = *(const float4*)(p0 + F_ + c);
        float4 g1 = *(const float4*)(p1 + F_ + c);
        float4 gb = *(const float4*)(fb + F_ + c);
        float a1[4] = {x0.x+x1.x+xb.x, x0.y+x1.y+xb.y, x0.z+x1.z+xb.z, x0.w+x1.w+xb.w};
        float a2[4] = {g0.x+g1.x+gb.x, g0.y+g1.y+gb.y, g0.z+g1.z+gb.z, g0.w+g1.w+gb.w};
        short4v o;
        #pragma unroll
        for (int j=0;j<4;j++) {
            float g = a2[j] * 0.5f * (1.0f + erff(a2[j] * 0.70710678118654752f));
            o[j] = f2bf(a1[j] * g);
        }
        *(short4v*)(aout + (size_t)t*F_ + c) = o;
    }
}

// fill buf rows with a bias vector (pre-fill for split-K accumulation)
__global__ __launch_bounds__(256) void bias_fill(
    const float* __restrict__ bias, float* __restrict__ buf, int width)
{
    const int row = blockIdx.x, tid = threadIdx.x;
    for (int c = tid*4; c < width; c += 1024) {
        float4 b = *(const float4*)(bias + c);
        *(float4*)(buf + (size_t)row*width + c) = b;
    }
}

// ===================== MFMA flash attention =====================
__global__ __launch_bounds__(128) void flash_attn(
    const float* __restrict__ qkv, const int* __restrict__ ids,
    short* __restrict__ attnout)
{
    const int h  = blockIdx.y;
    const int q0 = blockIdx.x * 32;
    const int tid = threadIdx.x;
    const int lane = tid & 63, w = tid >> 6;
    const int quad = lane >> 4, lm = lane & 15;

    __shared__ __align__(16) short Qs[32*72];
    __shared__ __align__(16) short Ks[64*72];
    __shared__ __align__(16) short Vt[64*72];
    __shared__ __align__(16) short Ps[2][16*72];
    __shared__ int globf[32];

    {
        int row = tid >> 2, c = (tid & 3) * 16;
        const float* qp = qkv + (size_t)(q0 + row) * D3_ + h * HD_ + c;
        float4 f0 = *(const float4*)(qp);
        float4 f1 = *(const float4*)(qp + 4);
        float4 f2 = *(const float4*)(qp + 8);
        float4 f3 = *(const float4*)(qp + 12);
        short8 s0, s1;
        cvt16(f0, f1, f2, f3, s0, s1);
        *(short8*)&Qs[row*72 + c]     = s0;
        *(short8*)&Qs[row*72 + c + 8] = s1;
    }
    if (tid < 32) {
        int id = ids[q0 + tid];
        globf[tid] = (id >= 2 && id <= 7) ? 1 : 0;
    }
    __syncthreads();

    FragU QA[2];
    #pragma unroll
    for (int s = 0; s < 2; s++)
        QA[s].s = *(short8*)&Qs[(w*16 + lm)*72 + s*32 + quad*8];

    int any = 0;
    #pragma unroll
    for (int i = 0; i < 32; i++) any |= globf[i];
    const int nt = any ? (T_/64) : ((q0 + 31) >> 6) + 1;

    int gq[4]; int qidx[4];
    #pragma unroll
    for (int r = 0; r < 4; r++) {
        int ql = w*16 + quad*4 + r;
        qidx[r] = q0 + ql;
        gq[r] = globf[ql];
    }

    float mrow[4] = {-1e30f, -1e30f, -1e30f, -1e30f};
    float lrow[4] = {0.f, 0.f, 0.f, 0.f};
    floatx4 Oacc[4];
    #pragma unroll
    for (int n = 0; n < 4; n++) Oacc[n] = (floatx4){0.f, 0.f, 0.f, 0.f};

    for (int kt = 0; kt < nt; kt++) {
        __syncthreads();
        #pragma unroll
        for (int rep = 0; rep < 2; rep++) {
            int key = (tid >> 2) + rep*32;
            int c = (tid & 3) * 16;
            const float* kp = qkv + (size_t)(kt*64 + key) * D3_ + D_ + h*HD_ + c;
            float4 f0 = *(const float4*)(kp);
            float4 f1 = *(const float4*)(kp + 4);
            float4 f2 = *(const float4*)(kp + 8);
            float4 f3 = *(const float4*)(kp + 12);
            short8 s0, s1;
            cvt16(f0, f1, f2, f3, s0, s1);
            *(short8*)&Ks[key*72 + c]     = s0;
            *(short8*)&Ks[key*72 + c + 8] = s1;
        }
        #pragma unroll
        for (int rep = 0; rep < 8; rep++) {
            int lin = tid + rep*128;
            int key = lin >> 4;
            int c = (lin & 15) * 4;
            const float* vp = qkv + (size_t)(kt*64 + key) * D3_ + 2*D_ + h*HD_ + c;
            float4 f = *(const float4*)vp;
            Vt[(c+0)*72 + key] = f2bf(f.x);
            Vt[(c+1)*72 + key] = f2bf(f.y);
            Vt[(c+2)*72 + key] = f2bf(f.z);
            Vt[(c+3)*72 + key] = f2bf(f.w);
        }
        __syncthreads();

        floatx4 Sv[4];
        #pragma unroll
        for (int n = 0; n < 4; n++) {
            Sv[n] = (floatx4){0.f, 0.f, 0.f, 0.f};
            #pragma unroll
            for (int s = 0; s < 2; s++) {
                FragU KB;
                KB.s = *(short8*)&Ks[(n*16 + lm)*72 + s*32 + quad*8];
                Sv[n] = __builtin_amdgcn_mfma_f32_16x16x32_bf16(QA[s].b, KB.b, Sv[n], 0, 0, 0);
            }
        }
        #pragma unroll
        for (int n = 0; n < 4; n++) {
            int key = kt*64 + n*16 + lm;
            #pragma unroll
            for (int r = 0; r < 4; r++) {
                float v = Sv[n][r] * 0.125f;
                if (!gq[r] && key > qidx[r]) v = -1e30f;
                Sv[n][r] = v;
            }
        }
        float mnew[4], alpha[4], tsum[4];
        #pragma unroll
        for (int r = 0; r < 4; r++) {
            float tm = fmaxf(fmaxf(Sv[0][r], Sv[1][r]), fmaxf(Sv[2][r], Sv[3][r]));
            #pragma unroll
            for (int x = 1; x < 16; x <<= 1) tm = fmaxf(tm, __shfl_xor(tm, x));
            mnew[r] = fmaxf(mrow[r], tm);
            alpha[r] = __expf(mrow[r] - mnew[r]);
            mrow[r] = mnew[r];
            tsum[r] = 0.f;
        }
        #pragma unroll
        for (int n = 0; n < 4; n++) {
            #pragma unroll
            for (int r = 0; r < 4; r++) {
                float p = __expf(Sv[n][r] - mnew[r]);
                tsum[r] += p;
                Ps[w][(quad*4 + r)*72 + n*16 + lm] = f2bf(p);
            }
        }
        #pragma unroll
        for (int r = 0; r < 4; r++) {
            #pragma unroll
            for (int x = 1; x < 16; x <<= 1) tsum[r] += __shfl_xor(tsum[r], x);
            lrow[r] = lrow[r] * alpha[r] + tsum[r];
        }
        #pragma unroll
        for (int n = 0; n < 4; n++)
            #pragma unroll
            for (int r = 0; r < 4; r++) Oacc[n][r] *= alpha[r];

        #pragma unroll
        for (int s = 0; s < 2; s++) {
            FragU PA;
            PA.s = *(short8*)&Ps[w][lm*72 + s*32 + quad*8];
            #pragma unroll
            for (int n = 0; n < 4; n++) {
                FragU VB;
                VB.s = *(short8*)&Vt[(n*16 + lm)*72 + s*32 + quad*8];
                Oacc[n] = __builtin_amdgcn_mfma_f32_16x16x32_bf16(PA.b, VB.b, Oacc[n], 0, 0, 0);
            }
        }
    }

    #pragma unroll
    for (int n = 0; n < 4; n++)
        #pragma unroll
        for (int r = 0; r < 4; r++) {
            float o = Oacc[n][r] / lrow[r];
            attnout[(size_t)qidx[r]*D_ + h*HD_ + n*16 + lm] = f2bf(o);
        }
}

// ===================== epilogues =====================
__global__ __launch_bounds__(256) void ep_attn(
    const float* __restrict__ x, const float* __restrict__ sacc,
    const float* __restrict__ aob, float* __restrict__ x2)
{
    int row = blockIdx.x, tid = threadIdx.x;
    float4 xv = ((const float4*)(x + (size_t)row*D_))[tid];
    float4 sv = ((const float4*)(sacc + (size_t)row*D_))[tid];
    float4 bv = ((const float4*)aob)[tid];
    float4 o;
    o.x = xv.x + sv.x + bv.x; o.y = xv.y + sv.y + bv.y;
    o.z = xv.z + sv.z + bv.z; o.w = xv.w + sv.w + bv.w;
    ((float4*)(x2 + (size_t)row*D_))[tid] = o;
}

__global__ __launch_bounds__(256) void ep_moe(
    const float* __restrict__ x2, const float* __restrict__ sacc,
    const float* __restrict__ eob, const float* __restrict__ gw,
    const int* __restrict__ gi, float* __restrict__ out)
{
    int row = blockIdx.x, tid = threadIdx.x;
    float g = gw[row];
    int e = gi[row];
    float4 xv = ((const float4*)(x2 + (size_t)row*D_))[tid];
    float4 sv = ((const float4*)(sacc + (size_t)row*D_))[tid];
    float4 bv = ((const float4*)(eob + (size_t)e*D_))[tid];
    float4 o;
    o.x = xv.x + g*(sv.x + bv.x); o.y = xv.y + g*(sv.y + bv.y);
    o.z = xv.z + g*(sv.z + bv.z); o.w = xv.w + g*(sv.w + bv.w);
    ((float4*)(out + (size_t)row*D_))[tid] = o;
}

// ===================== small kernels =====================
__global__ __launch_bounds__(256) void ln_kernel(
    const float* __restrict__ x, const float* __restrict__ w,
    const float* __restrict__ b, short* __restrict__ out)   // bf16 out
{
    const int row = blockIdx.x, tid = threadIdx.x;
    const int lane = tid & 63, wave = tid >> 6;
    float4 v = ((const float4*)(x + (size_t)row * D_))[tid];
    float s  = v.x + v.y + v.z + v.w;
    float sq = v.x*v.x + v.y*v.y + v.z*v.z + v.w*v.w;
    #pragma unroll
    for (int off = 32; off; off >>= 1) {
        s  += __shfl_down(s, off);
        sq += __shfl_down(sq, off);
    }
    __shared__ float rs[4], rq[4], mv[2];
    if (lane == 0) { rs[wave] = s; rq[wave] = sq; }
    __syncthreads();
    if (tid == 0) {
        float ts = rs[0]+rs[1]+rs[2]+rs[3];
        float tq = rq[0]+rq[1]+rq[2]+rq[3];
        float mean = ts * (1.0f / D_);
        float var  = tq * (1.0f / D_) - mean*mean;
        mv[0] = mean; mv[1] = rsqrtf(var + 1e-5f);
    }
    __syncthreads();
    float mean = mv[0], rstd = mv[1];
    float4 wv = ((const float4*)w)[tid];
    float4 bv = ((const float4*)b)[tid];
    short4v o;
    o[0] = f2bf((v.x-mean)*rstd*wv.x + bv.x);
    o[1] = f2bf((v.y-mean)*rstd*wv.y + bv.y);
    o[2] = f2bf((v.z-mean)*rstd*wv.z + bv.z);
    o[3] = f2bf((v.w-mean)*rstd*wv.w + bv.w);
    ((short4v*)(out + (size_t)row * D_))[tid] = o;
}

__global__ __launch_bounds__(256) void rope_kernel(float* __restrict__ qkv)
{
    int gid = blockIdx.x * 256 + threadIdx.x;
    int t = gid >> 9;
    int r = gid & 511;
    int h = r >> 5;
    int d = r & 31;
    float inv = exp2f((float)d * -0.4152410118609203f);
    float fr = (float)t * inv;
    float s, c;
    sincosf(fr, &s, &c);
    float* base = qkv + (size_t)t*D3_ + h*HD_ + d;
    float q1 = base[0], q2 = base[32];
    base[0]  = q1*c - q2*s;
    base[32] = q1*s + q2*c;
    float* kb = base + D_;
    float k1 = kb[0], k2 = kb[32];
    kb[0]  = k1*c - k2*s;
    kb[32] = k1*s + k2*c;
}

__global__ __launch_bounds__(256) void ln2_gate_kernel(
    const float* __restrict__ x2, const float* __restrict__ w,
    const float* __restrict__ b, const float* __restrict__ gwm,
    const float* __restrict__ gbv, short* __restrict__ h2,   // bf16 out
    int* __restrict__ gi, float* __restrict__ gw)
{
    const int row = blockIdx.x, tid = threadIdx.x;
    const int lane = tid & 63, wave = tid >> 6;
    float4 v = ((const float4*)(x2 + (size_t)row * D_))[tid];
    float s  = v.x + v.y + v.z + v.w;
    float sq = v.x*v.x + v.y*v.y + v.z*v.z + v.w*v.w;
    #pragma unroll
    for (int off = 32; off; off >>= 1) {
        s  += __shfl_down(s, off);
        sq += __shfl_down(sq, off);
    }
    __shared__ float rs[4], rq[4], mv[2];
    if (lane == 0) { rs[wave] = s; rq[wave] = sq; }
    __syncthreads();
    if (tid == 0) {
        float ts = rs[0]+rs[1]+rs[2]+rs[3];
        float tq = rq[0]+rq[1]+rq[2]+rq[3];
        float mean = ts * (1.0f / D_);
        float var  = tq * (1.0f / D_) - mean*mean;
        mv[0] = mean; mv[1] = rsqrtf(var + 1e-5f);
    }
    __syncthreads();
    float mean = mv[0], rstd = mv[1];
    float4 wv = ((const float4*)w)[tid];
    float4 bv = ((const float4*)b)[tid];
    float hv[4];
    hv[0] = (v.x-mean)*rstd*wv.x + bv.x;
    hv[1] = (v.y-mean)*rstd*wv.y + bv.y;
    hv[2] = (v.z-mean)*rstd*wv.z + bv.z;
    hv[3] = (v.w-mean)*rstd*wv.w + bv.w;
    short4v o;
    o[0]=f2bf(hv[0]); o[1]=f2bf(hv[1]); o[2]=f2bf(hv[2]); o[3]=f2bf(hv[3]);
    ((short4v*)(h2 + (size_t)row * D_))[tid] = o;

    float acc[E_] = {};
    int c = tid * 4;
    #pragma unroll
    for (int j = 0; j < 4; j++) {
        const float* gr = gwm + (size_t)(c+j) * E_;
        #pragma unroll
        for (int e = 0; e < E_; e++) acc[e] += hv[j] * gr[e];
    }
    #pragma unroll
    for (int off = 32; off; off >>= 1)
        #pragma unroll
        for (int e = 0; e < E_; e++) acc[e] += __shfl_down(acc[e], off);
    __shared__ float gred[4][E_];
    if (lane == 0)
        for (int e = 0; e < E_; e++) gred[wave][e] = acc[e];
    __syncthreads();
    if (tid == 0) {
        float lg[E_];
        float mxl = -FLT_MAX; int mi = 0;
        for (int e = 0; e < E_; e++)
            lg[e] = gred[0][e]+gred[1][e]+gred[2][e]+gred[3][e] + gbv[e];
        for (int e = 0; e < E_; e++)
            if (lg[e] > mxl) { mxl = lg[e]; mi = e; }
        float ssum = 0.f;
        for (int e = 0; e < E_; e++) ssum += expf(lg[e] - mxl);
        gi[row] = mi;
        gw[row] = 1.0f / ssum;
    }
}

__global__ void route_kernel(const int* __restrict__ gi,
                             int* __restrict__ offs, int* __restrict__ perm)
{
    __shared__ int cnt[E_], c2[E_], off[E_+1];
    const int tid = threadIdx.x;
    if (tid < E_) { cnt[tid] = 0; c2[tid] = 0; }
    __syncthreads();
    int e = gi[tid];
    atomicAdd(&cnt[e], 1);
    __syncthreads();
    if (tid == 0) {
        off[0] = 0;
        for (int i = 0; i < E_; i++) off[i+1] = off[i] + cnt[i];
        for (int i = 0; i <= E_; i++) offs[i] = off[i];
    }
    __syncthreads();
    int r = atomicAdd(&c2[e], 1);
    perm[off[e] + r] = tid;
}

__global__ void loss_kernel(const int* __restrict__ gi,
                            const float* __restrict__ gw, float* __restrict__ out)
{
    __shared__ float ss[E_], sc[E_];
    const int tid = threadIdx.x;
    if (tid < E_) { ss[tid] = 0.f; sc[tid] = 0.f; }
    __syncthreads();
    for (int t = tid; t < T_; t += 256) {
        int e = gi[t];
        atomicAdd(&ss[e], gw[t]);
        atomicAdd(&sc[e], 1.0f);
    }
    __syncthreads();
    if (tid == 0) {
        float loss = 0.f;
        for (int e = 0; e < E_; e++) {
            float u = ss[e] / (sc[e] + 1e-8f);
            float d = u - 0.125f;
            loss += d * d;
        }
        out[(size_t)T_ * D_] = loss;
    }
}

extern "C" void kernel_launch(void* const* d_in, const int* in_sizes, int n_in,
                              void* d_out, int out_size, void* d_ws, size_t ws_size,
                              hipStream_t stream)
{
    const float* x     = (const float*)d_in[0];
    const int*   ids   = (const int*)d_in[1];
    const float* ln1w  = (const float*)d_in[2];
    const float* ln1b  = (const float*)d_in[3];
    const float* qkvw  = (const float*)d_in[4];
    const float* qkvb  = (const float*)d_in[5];
    const float* aow   = (const float*)d_in[6];
    const float* aob   = (const float*)d_in[7];
    const float* ln2w  = (const float*)d_in[8];
    const float* ln2b  = (const float*)d_in[9];
    const float* gatew = (const float*)d_in[10];
    const float* gateb = (const float*)d_in[11];
    const float* fcw   = (const float*)d_in[12];
    const float* fcb   = (const float*)d_in[13];
    const float* eoutw = (const float*)d_in[14];
    const float* eoutb = (const float*)d_in[15];
    float* out = (float*)d_out;
    float* ws  = (float*)d_ws;

    short* hb    = (short*)(ws + WS_H);   // bf16 LN1 out; slot reused as SACC later
    float* sacc  = ws + WS_H;
    float* qkv   = ws + WS_QKV;
    short* attnb = (short*)(ws + WS_ATTN);
    float* x2    = ws + WS_X2;
    short* h2b   = (short*)(ws + WS_H2);
    short* abuf  = (short*)(ws + WS_A);
    float* gw    = ws + WS_GW;
    int*   gi    = (int*)(ws + WS_GI);
    int*   offs  = (int*)(ws + WS_OFFS);
    int*   perm  = (int*)(ws + WS_PERM);
    float* h12   = ws + WS_H12;           // 2 x (T,F2) split-K partials

    // 1. LN1 (bf16 out)
    ln_kernel<<<T_, 256, 0, stream>>>(x, ln1w, ln1b, hb);
    // 2. QKV projection: bias pre-fill + split-K=2 accumulating GEMM (Kp=512)
    bias_fill<<<T_, 256, 0, stream>>>(qkvb, qkv, D3_);
    gemm_mfma_acc<<<dim3(D3_/64, 2, T_/128), 256, 0, stream>>>(
        hb, D_, qkvw, D3_, 0, nullptr, nullptr, qkv, D3_, D_, 2);
    // 3. RoPE
    rope_kernel<<<(T_*H_*32)/256, 256, 0, stream>>>(qkv);
    // 4. MFMA flash attention (bf16 out)
    flash_attn<<<dim3(T_/32, H_), 128, 0, stream>>>(qkv, ids, attnb);
    // 5. zero split-K accumulator
    hipMemsetAsync(sacc, 0, (size_t)T_*D_*sizeof(float), stream);
    // 6. attn output projection (split-K=4, Kp=256)
    gemm_mfma_acc<<<dim3(D_/64, 4, T_/128), 256, 0, stream>>>(
        attnb, D_, aow, D_, 0, nullptr, nullptr, sacc, D_, D_, 4);
    // 7. residual + bias
    ep_attn<<<T_, 256, 0, stream>>>(x, sacc, aob, x2);
    // 8. LN2 + gate (bf16 h2)
    ln2_gate_kernel<<<T_, 256, 0, stream>>>(x2, ln2w, ln2b, gatew, gateb, h2b, gi, gw);
    // 9. routing
    route_kernel<<<1, T_, 0, stream>>>(gi, offs, perm);
    // 10. expert fc: split-K=2 (Kp=512), direct dual-buffer stores
    gemm_fc_sk<<<dim3(F2_/64, 2*E_, T_/128), 256, 0, stream>>>(h2b, fcw, offs, perm, h12);
    // 10b. GLU epilogue (sum halves + bias + gelu), bf16 out
    glu_kernel<<<T_, 256, 0, stream>>>(h12, fcb, gi, abuf);
    // 11. re-zero accumulator
    hipMemsetAsync(sacc, 0, (size_t)T_*D_*sizeof(float), stream);
    // 12. expert out (split-K=4, Kp=640, routed)
    gemm_mfma_acc<<<dim3(D_/64, 4*E_, T_/128), 256, 0, stream>>>(
        abuf, F_, eoutw, D_, (long)F_*D_, offs, perm, sacc, D_, F_, 4);
    // 13. residual + gate scale + bias
    ep_moe<<<T_, 256, 0, stream>>>(x2, sacc, eoutb, gw, gi, out);
    // 14. aux loss
    loss_kernel<<<1, 256, 0, stream>>>(gi, gw, out);
}